// Round 4
// baseline (647.572 us; speedup 1.0000x reference)
//
#include <hip/hip_runtime.h>
#include <math.h>

#define HPIX 256
#define WPIX 256
#define NPIX (HPIX * WPIX)
#define DIM 96
#define QKVC 288
#define NHEAD 8
#define CPH 12
#define EPSN 1e-12f
#define PSTRIDE 544  // per (b,g,chunk) partial record: 256 gqk + 256 gmm + 16 dq + 16 dk

typedef __attribute__((ext_vector_type(8))) short bf16x8;
typedef __attribute__((ext_vector_type(4))) float f32x4;

__device__ __forceinline__ unsigned short f2bf(float f) {
  unsigned u = __float_as_uint(f);
  u += 0x7FFF + ((u >> 16) & 1);  // RNE
  return (unsigned short)(u >> 16);
}
__device__ __forceinline__ float bf2f(unsigned short h) {
  return __uint_as_float((unsigned)h << 16);
}

// ---------------- K1/K5: 1x1 conv as MFMA GEMM, split-bf16 hi/lo -------------
// out[oc][p] = sum_ic w[oc][ic] x[ic][p].  grid (NPIX/64, OC/32, nb), block 256
template<int OC>
__global__ __launch_bounds__(256) void k_gemm1x1(
    const float* __restrict__ xin, const float* __restrict__ w,
    float* __restrict__ out) {
  __shared__ __align__(16) unsigned short xhi[64][104];
  __shared__ __align__(16) unsigned short xlo[64][104];
  __shared__ __align__(16) unsigned short whi[32][104];
  __shared__ __align__(16) unsigned short wlo[32][104];
  int t = threadIdx.x;
  int p0 = blockIdx.x * 64;
  int ob = blockIdx.y * 32;
  const float* xb = xin + (size_t)blockIdx.z * DIM * NPIX + p0;

  // stage W tile 32x96 (hi/lo bf16)
  {
    int o = t >> 3, kb = (t & 7) * 12;
    const float* wp = w + (size_t)(ob + o) * DIM + kb;
    #pragma unroll
    for (int i = 0; i < 12; ++i) {
      float v = wp[i];
      unsigned short h = f2bf(v);
      whi[o][kb + i] = h;
      wlo[o][kb + i] = f2bf(v - bf2f(h));
    }
  }
  // stage X tile 96k x 64px, transposed to [px][k] (hi/lo bf16)
  #pragma unroll
  for (int r = 0; r < 6; ++r) {
    int idx = t + 256 * r;   // float4 index in [0,1536)
    int k = idx >> 4;        // 16 float4 per k-row
    int f4 = idx & 15;
    float4 v = *(const float4*)(xb + (size_t)k * NPIX + f4 * 4);
    int px = f4 * 4;
    float vv[4] = {v.x, v.y, v.z, v.w};
    #pragma unroll
    for (int c = 0; c < 4; ++c) {
      unsigned short h = f2bf(vv[c]);
      xhi[px + c][k] = h;
      xlo[px + c][k] = f2bf(vv[c] - bf2f(h));
    }
  }
  __syncthreads();

  int lane = t & 63;
  int wv = t >> 6;            // wave id -> 16-px slice
  int row16 = lane & 15, kg = lane >> 4;

  f32x4 acc[2] = {{0.f, 0.f, 0.f, 0.f}, {0.f, 0.f, 0.f, 0.f}};
  #pragma unroll
  for (int ks = 0; ks < 3; ++ks) {
    int kc = ks * 32 + kg * 8;
    bf16x8 bh = *(const bf16x8*)&xhi[wv * 16 + row16][kc];
    bf16x8 bl = *(const bf16x8*)&xlo[wv * 16 + row16][kc];
    #pragma unroll
    for (int mi = 0; mi < 2; ++mi) {
      bf16x8 ah = *(const bf16x8*)&whi[mi * 16 + row16][kc];
      bf16x8 al = *(const bf16x8*)&wlo[mi * 16 + row16][kc];
      acc[mi] = __builtin_amdgcn_mfma_f32_16x16x32_bf16(ah, bh, acc[mi], 0, 0, 0);
      acc[mi] = __builtin_amdgcn_mfma_f32_16x16x32_bf16(ah, bl, acc[mi], 0, 0, 0);
      acc[mi] = __builtin_amdgcn_mfma_f32_16x16x32_bf16(al, bh, acc[mi], 0, 0, 0);
    }
  }

  float* op = out + (size_t)blockIdx.z * OC * NPIX + p0 + wv * 16 + row16;
  #pragma unroll
  for (int mi = 0; mi < 2; ++mi) {
    #pragma unroll
    for (int j = 0; j < 4; ++j) {
      int o = ob + mi * 16 + kg * 4 + j;  // C/D: row=(lane>>4)*4+j, col=lane&15
      op[(size_t)o * NPIX] = acc[mi][j];
    }
  }
}

// ---------------- K2: depthwise 3x3, zero pad 1, 4 px per thread ----------------
// grid (NPIX/1024, 288, nb), block 256
__global__ __launch_bounds__(256) void k_dw3x3(
    const float* __restrict__ in, const float* __restrict__ w,
    float* __restrict__ out) {
  int t = threadIdx.x;
  int p0 = (blockIdx.x * 256 + t) * 4;
  int ch = blockIdx.y;
  size_t base = ((size_t)blockIdx.z * QKVC + ch) * NPIX;
  int y = p0 >> 8, x0 = p0 & 255;
  const float* wc = w + ch * 9;
  float a0 = 0.f, a1 = 0.f, a2 = 0.f, a3 = 0.f;
  #pragma unroll
  for (int dy = -1; dy <= 1; ++dy) {
    int yy = y + dy;
    if (yy < 0 || yy >= HPIX) continue;
    const float* row = in + base + (size_t)yy * WPIX + x0;
    float4 c = *(const float4*)row;
    float l = (x0 > 0) ? row[-1] : 0.f;
    float r = (x0 < 252) ? row[4] : 0.f;
    float w0 = wc[(dy + 1) * 3], w1 = wc[(dy + 1) * 3 + 1], w2 = wc[(dy + 1) * 3 + 2];
    a0 = fmaf(w0, l,   fmaf(w1, c.x, fmaf(w2, c.y, a0)));
    a1 = fmaf(w0, c.x, fmaf(w1, c.y, fmaf(w2, c.z, a1)));
    a2 = fmaf(w0, c.y, fmaf(w1, c.z, fmaf(w2, c.w, a2)));
    a3 = fmaf(w0, c.z, fmaf(w1, c.w, fmaf(w2, r,   a3)));
  }
  *(float4*)(out + base + p0) = make_float4(a0, a1, a2, a3);
}

// ---------------- K3a: per-(b,g,chunk) partial grams + row norms ----------------
// grid (96, 16, nb), block 256. thread t -> (n = t>>4, m = t&15)
__global__ __launch_bounds__(256) void k_attn_part(
    const float* __restrict__ qkv2, const float* __restrict__ mask,
    float* __restrict__ pbuf, int b0) {
  int g = blockIdx.x;
  int c = blockIdx.y;
  int lb = blockIdx.z;
  int t = threadIdx.x;
  int n = t >> 4, m = t & 15;

  __shared__ float qT[16 * 260];
  __shared__ float kT[16 * 260];
  __shared__ float mT[16 * 260];

  const float* qb = qkv2 + ((size_t)lb * QKVC + g) * NPIX;
  const float* kb = qkv2 + ((size_t)lb * QKVC + DIM + g) * NPIX;
  const float* mb = mask + ((size_t)(b0 + lb) * DIM + g) * NPIX;

  int hh0 = (c << 2) + (t >> 6);
  int w0 = t & 63;
  #pragma unroll
  for (int r = 0; r < 16; ++r) {  // r = spatial block h1*4+w1
    size_t off = (size_t)(((r >> 2) << 6) + hh0) * WPIX + ((r & 3) << 6) + w0;
    qT[r * 260 + t] = qb[off];
    kT[r * 260 + t] = kb[off];
    mT[r * 260 + t] = mb[off];
  }
  __syncthreads();

  float gqk = 0.f, gmm = 0.f, dq = 0.f, dk = 0.f;
  const float4* q4  = (const float4*)(qT + n * 260);
  const float4* k4  = (const float4*)(kT + m * 260);
  const float4* mn4 = (const float4*)(mT + n * 260);
  const float4* mm4 = (const float4*)(mT + m * 260);
  #pragma unroll 4
  for (int jq = 0; jq < 64; ++jq) {
    float4 a = q4[jq], b = k4[jq];
    gqk = fmaf(a.x, b.x, fmaf(a.y, b.y, fmaf(a.z, b.z, fmaf(a.w, b.w, gqk))));
    float4 cc = mn4[jq], d = mm4[jq];
    gmm = fmaf(cc.x, d.x, fmaf(cc.y, d.y, fmaf(cc.z, d.z, fmaf(cc.w, d.w, gmm))));
  }
  const float* qr = qT + n * 260;
  const float* kr = kT + n * 260;
  #pragma unroll
  for (int jj = 0; jj < 16; ++jj) {
    float qv = qr[m + 16 * jj]; dq = fmaf(qv, qv, dq);
    float kv = kr[m + 16 * jj]; dk = fmaf(kv, kv, dk);
  }
  #pragma unroll
  for (int off = 8; off; off >>= 1) {
    dq += __shfl_xor(dq, off, 16);
    dk += __shfl_xor(dk, off, 16);
  }

  float* pb = pbuf + (((size_t)lb * DIM + g) * 16 + c) * PSTRIDE;
  pb[t] = gqk;
  pb[256 + t] = gmm;
  if (m == 0) { pb[512 + n] = dq; pb[528 + n] = dk; }
}

// ---------------- K3b: reduce partials + softmax chain -> attn[16][16] ---------
// grid (96, nb), block 256
__global__ __launch_bounds__(256) void k_attn_fin(
    const float* __restrict__ pbuf, const float* __restrict__ tx,
    const float* __restrict__ tm, float* __restrict__ attnbuf) {
  int g = blockIdx.x;
  int lb = blockIdx.y;
  int h = g / CPH;
  int t = threadIdx.x;
  int n = t >> 4, m = t & 15;

  const float* pb = pbuf + ((size_t)lb * DIM + g) * 16 * PSTRIDE;
  float gqk = 0.f, gmm = 0.f, dq = 0.f, dk = 0.f;
  #pragma unroll
  for (int c = 0; c < 16; ++c) {
    const float* p = pb + c * PSTRIDE;
    gqk += p[t];
    gmm += p[256 + t];
    dq  += p[512 + n];
    dk  += p[528 + m];
  }

  float qn = fmaxf(sqrtf(dq), EPSN);
  float km = fmaxf(sqrtf(dk), EPSN);

  float ax = gqk / (qn * km) * tx[h];
  float r0 = ax;
  #pragma unroll
  for (int off = 8; off; off >>= 1) r0 = fmaxf(r0, __shfl_xor(r0, off, 16));
  float e0 = expf(ax - r0), es0 = e0;
  #pragma unroll
  for (int off = 8; off; off >>= 1) es0 += __shfl_xor(es0, off, 16);
  float attx = e0 / es0;

  float am = gmm * tm[h];
  float s2 = am * am;
  #pragma unroll
  for (int off = 8; off; off >>= 1) s2 += __shfl_xor(s2, off, 16);
  am = am / fmaxf(sqrtf(s2), EPSN);
  float r1 = am;
  #pragma unroll
  for (int off = 8; off; off >>= 1) r1 = fmaxf(r1, __shfl_xor(r1, off, 16));
  float e1 = expf(am - r1), es1 = e1;
  #pragma unroll
  for (int off = 8; off; off >>= 1) es1 += __shfl_xor(es1, off, 16);
  float attm = e1 / es1;

  float aa = attx + attm;
  float r2 = aa;
  #pragma unroll
  for (int off = 8; off; off >>= 1) r2 = fmaxf(r2, __shfl_xor(r2, off, 16));
  float e2 = expf(aa - r2), es2 = e2;
  #pragma unroll
  for (int off = 8; off; off >>= 1) es2 += __shfl_xor(es2, off, 16);

  attnbuf[(((size_t)lb * DIM + g) << 8) + t] = e2 / es2;
}

// ---------------- K4: out_blk = attn @ v, written un-blockified ----------------
// grid (64 (hh), 96 (g), nb), block 256
__global__ __launch_bounds__(256) void k_pv(
    const float* __restrict__ qkv2, const float* __restrict__ attnbuf,
    float* __restrict__ tout) {
  int hh = blockIdx.x;
  int g = blockIdx.y;
  int lb = blockIdx.z;
  int t = threadIdx.x;
  int ww = t & 63, grp = t >> 6;

  __shared__ float vt[16][64];
  __shared__ float at[16][16];

  const float* vb = qkv2 + ((size_t)lb * QKVC + 2 * DIM + g) * NPIX;
  #pragma unroll
  for (int jj = 0; jj < 4; ++jj) {
    int mm = jj * 4 + grp;
    vt[mm][ww] = vb[(size_t)(((mm >> 2) << 6) + hh) * WPIX + ((mm & 3) << 6) + ww];
  }
  at[t >> 4][t & 15] = attnbuf[(((size_t)lb * DIM + g) << 8) + t];
  __syncthreads();

  float* ob = tout + ((size_t)lb * DIM + g) * NPIX;
  #pragma unroll
  for (int jj = 0; jj < 4; ++jj) {
    int nn = jj * 4 + grp;
    float acc = 0.f;
    #pragma unroll
    for (int mm = 0; mm < 16; ++mm)
      acc = fmaf(at[nn][mm], vt[mm][ww], acc);
    ob[(size_t)(((nn >> 2) << 6) + hh) * WPIX + ((nn & 3) << 6) + ww] = acc;
  }
}

extern "C" void kernel_launch(void* const* d_in, const int* in_sizes, int n_in,
                              void* d_out, int out_size, void* d_ws, size_t ws_size,
                              hipStream_t stream) {
  const float* x      = (const float*)d_in[0];
  const float* mask   = (const float*)d_in[1];
  const float* w_qkv  = (const float*)d_in[2];
  const float* w_dw   = (const float*)d_in[3];
  const float* w_proj = (const float*)d_in[4];
  const float* tx     = (const float*)d_in[5];
  const float* tm     = (const float*)d_in[6];
  float* out = (float*)d_out;

  const size_t qkvBytes = (size_t)QKVC * NPIX * sizeof(float);  // 75.5 MB per batch
  const size_t attnBytesPerB = (size_t)DIM * 256 * sizeof(float);

  int nb, npass;
  if (ws_size >= 8 * qkvBytes + 4 * attnBytesPerB) { nb = 4; npass = 1; }
  else                                             { nb = 1; npass = 4; }

  char* base = (char*)d_ws;
  float* qkv1 = (float*)base;                                   // nb * qkvBytes (later reused as t)
  float* qkv2 = (float*)(base + (size_t)nb * qkvBytes);         // nb * qkvBytes
  float* attn = (float*)(base + 2 * (size_t)nb * qkvBytes);     // nb * attnBytesPerB
  float* tbuf = qkv1;  // alias: qkv1 dead after k_dw3x3
  float* pbuf = qkv1 + (size_t)nb * DIM * NPIX;  // past tbuf region

  dim3 blk(256);
  for (int pass = 0; pass < npass; ++pass) {
    int b0 = pass * nb;
    const float* xb = x + (size_t)b0 * DIM * NPIX;
    k_gemm1x1<QKVC><<<dim3(NPIX / 64, QKVC / 32, nb), blk, 0, stream>>>(xb, w_qkv, qkv1);
    k_dw3x3<<<dim3(NPIX / 1024, QKVC, nb), blk, 0, stream>>>(qkv1, w_dw, qkv2);
    k_attn_part<<<dim3(DIM, 16, nb), blk, 0, stream>>>(qkv2, mask, pbuf, b0);
    k_attn_fin<<<dim3(DIM, nb), blk, 0, stream>>>(pbuf, tx, tm, attn);
    k_pv<<<dim3(64, DIM, nb), blk, 0, stream>>>(qkv2, attn, tbuf);
    k_gemm1x1<DIM><<<dim3(NPIX / 64, DIM / 32, nb), blk, 0, stream>>>(
        tbuf, w_proj, out + (size_t)b0 * DIM * NPIX);
  }
}

// Round 5
// 543.804 us; speedup vs baseline: 1.1908x; 1.1908x over previous
//
#include <hip/hip_runtime.h>
#include <math.h>

#define HPIX 256
#define WPIX 256
#define NPIX (HPIX * WPIX)
#define DIM 96
#define QKVC 288
#define NHEAD 8
#define CPH 12
#define EPSN 1e-12f
#define PSTRIDE 544  // per (b,g,chunk) partial record: 256 gqk + 256 gmm + 16 dq + 16 dk

typedef __attribute__((ext_vector_type(8))) short bf16x8;
typedef __attribute__((ext_vector_type(4))) float f32x4;

__device__ __forceinline__ unsigned short f2bf(float f) {
  unsigned u = __float_as_uint(f);
  u += 0x7FFF + ((u >> 16) & 1);  // RNE
  return (unsigned short)(u >> 16);
}
__device__ __forceinline__ float bf2f(unsigned short h) {
  return __uint_as_float((unsigned)h << 16);
}

// ---------------- K0: split weights into bf16 hi/lo (once per launch) --------
// grid 108 x 256 covers 288*96; proj subset i < 96*96
__global__ __launch_bounds__(256) void k_wprep(
    const float* __restrict__ wq, const float* __restrict__ wp,
    unsigned short* __restrict__ wqh, unsigned short* __restrict__ wql,
    unsigned short* __restrict__ wph, unsigned short* __restrict__ wpl) {
  int i = blockIdx.x * 256 + threadIdx.x;
  if (i < QKVC * DIM) {
    float v = wq[i];
    unsigned short h = f2bf(v);
    wqh[i] = h;
    wql[i] = f2bf(v - bf2f(h));
  }
  if (i < DIM * DIM) {
    float v = wp[i];
    unsigned short h = f2bf(v);
    wph[i] = h;
    wpl[i] = f2bf(v - bf2f(h));
  }
}

// ---------------- K1/K5: 1x1 conv MFMA GEMM, full-OC per 64-px block ---------
// out[oc][p] = sum_ic w[oc][ic] x[ic][p].  grid (NPIX/64, nb), block 256
// X staged hi/lo bf16 in LDS: row px (stride 128 shorts), 8-k units XOR-swizzled.
template<int OC>
__global__ __launch_bounds__(256) void k_gemm1x1(
    const float* __restrict__ xin,
    const unsigned short* __restrict__ wh, const unsigned short* __restrict__ wl,
    float* __restrict__ out) {
  __shared__ __align__(16) unsigned short xhi[64 * 128];
  __shared__ __align__(16) unsigned short xlo[64 * 128];
  int t = threadIdx.x;
  int p0 = blockIdx.x * 64;
  const float* xb = xin + (size_t)blockIdx.y * DIM * NPIX + p0;

  // stage: thread (kg, f4) loads 8 k-rows x 4 px, transposes in regs,
  // writes one b128 per px per buffer.
  if (t < 192) {
    int kg = t >> 4;   // 0..11 (8-k group)
    int f4 = t & 15;   // float4 column
    float4 v[8];
    #pragma unroll
    for (int i = 0; i < 8; ++i)
      v[i] = *(const float4*)(xb + (size_t)(kg * 8 + i) * NPIX + f4 * 4);
    #pragma unroll
    for (int c = 0; c < 4; ++c) {
      int px = f4 * 4 + c;
      int u = kg ^ ((px & 7) ^ ((px >> 3) & 7));
      bf16x8 hv, lv;
      #pragma unroll
      for (int i = 0; i < 8; ++i) {
        float vv = ((const float*)&v[i])[c];
        unsigned short h = f2bf(vv);
        hv[i] = (short)h;
        lv[i] = (short)f2bf(vv - bf2f(h));
      }
      *(bf16x8*)&xhi[px * 128 + u * 8] = hv;
      *(bf16x8*)&xlo[px * 128 + u * 8] = lv;
    }
  }
  __syncthreads();

  int lane = t & 63, wv = t >> 6;
  int r16 = lane & 15, kg8 = lane >> 4;
  int px = wv * 16 + r16;
  int swz = (px & 7) ^ ((px >> 3) & 7);

  // B fragments (X) for all 3 k-steps, hoisted
  bf16x8 bh[3], bl[3];
  #pragma unroll
  for (int ks = 0; ks < 3; ++ks) {
    int u = (ks * 4 + kg8) ^ swz;
    bh[ks] = *(const bf16x8*)&xhi[px * 128 + u * 8];
    bl[ks] = *(const bf16x8*)&xlo[px * 128 + u * 8];
  }

  f32x4 acc[OC / 16];
  #pragma unroll
  for (int mi = 0; mi < OC / 16; ++mi) acc[mi] = (f32x4){0.f, 0.f, 0.f, 0.f};

  #pragma unroll
  for (int mi = 0; mi < OC / 16; ++mi) {
    #pragma unroll
    for (int ks = 0; ks < 3; ++ks) {
      size_t woff = (size_t)(mi * 16 + r16) * DIM + ks * 32 + kg8 * 8;
      bf16x8 ah = *(const bf16x8*)(wh + woff);
      bf16x8 al = *(const bf16x8*)(wl + woff);
      acc[mi] = __builtin_amdgcn_mfma_f32_16x16x32_bf16(ah, bh[ks], acc[mi], 0, 0, 0);
      acc[mi] = __builtin_amdgcn_mfma_f32_16x16x32_bf16(ah, bl[ks], acc[mi], 0, 0, 0);
      acc[mi] = __builtin_amdgcn_mfma_f32_16x16x32_bf16(al, bh[ks], acc[mi], 0, 0, 0);
    }
  }

  float* op = out + (size_t)blockIdx.y * OC * NPIX + p0 + wv * 16 + r16;
  #pragma unroll
  for (int mi = 0; mi < OC / 16; ++mi) {
    #pragma unroll
    for (int j = 0; j < 4; ++j) {
      int o = mi * 16 + kg8 * 4 + j;  // C/D: row=(lane>>4)*4+j, col=lane&15
      op[(size_t)o * NPIX] = acc[mi][j];
    }
  }
}

// ---------------- K2: depthwise 3x3, zero pad 1, 4 px per thread ----------------
// grid (NPIX/1024, 288, nb), block 256
__global__ __launch_bounds__(256) void k_dw3x3(
    const float* __restrict__ in, const float* __restrict__ w,
    float* __restrict__ out) {
  int t = threadIdx.x;
  int p0 = (blockIdx.x * 256 + t) * 4;
  int ch = blockIdx.y;
  size_t base = ((size_t)blockIdx.z * QKVC + ch) * NPIX;
  int y = p0 >> 8, x0 = p0 & 255;
  const float* wc = w + ch * 9;
  float a0 = 0.f, a1 = 0.f, a2 = 0.f, a3 = 0.f;
  #pragma unroll
  for (int dy = -1; dy <= 1; ++dy) {
    int yy = y + dy;
    if (yy < 0 || yy >= HPIX) continue;
    const float* row = in + base + (size_t)yy * WPIX + x0;
    float4 c = *(const float4*)row;
    float l = (x0 > 0) ? row[-1] : 0.f;
    float r = (x0 < 252) ? row[4] : 0.f;
    float w0 = wc[(dy + 1) * 3], w1 = wc[(dy + 1) * 3 + 1], w2 = wc[(dy + 1) * 3 + 2];
    a0 = fmaf(w0, l,   fmaf(w1, c.x, fmaf(w2, c.y, a0)));
    a1 = fmaf(w0, c.x, fmaf(w1, c.y, fmaf(w2, c.z, a1)));
    a2 = fmaf(w0, c.y, fmaf(w1, c.z, fmaf(w2, c.w, a2)));
    a3 = fmaf(w0, c.z, fmaf(w1, c.w, fmaf(w2, r,   a3)));
  }
  *(float4*)(out + base + p0) = make_float4(a0, a1, a2, a3);
}

// ---------------- K3a: per-(b,g,chunk) partial grams + row norms ----------------
// grid (96, 16, nb), block 256. thread t -> (n = t>>4, m = t&15)
__global__ __launch_bounds__(256) void k_attn_part(
    const float* __restrict__ qkv2, const float* __restrict__ mask,
    float* __restrict__ pbuf, int b0) {
  int g = blockIdx.x;
  int c = blockIdx.y;
  int lb = blockIdx.z;
  int t = threadIdx.x;
  int n = t >> 4, m = t & 15;

  __shared__ float qT[16 * 260];
  __shared__ float kT[16 * 260];
  __shared__ float mT[16 * 260];

  const float* qb = qkv2 + ((size_t)lb * QKVC + g) * NPIX;
  const float* kb = qkv2 + ((size_t)lb * QKVC + DIM + g) * NPIX;
  const float* mb = mask + ((size_t)(b0 + lb) * DIM + g) * NPIX;

  int hh0 = (c << 2) + (t >> 6);
  int w0 = t & 63;
  #pragma unroll
  for (int r = 0; r < 16; ++r) {  // r = spatial block h1*4+w1
    size_t off = (size_t)(((r >> 2) << 6) + hh0) * WPIX + ((r & 3) << 6) + w0;
    qT[r * 260 + t] = qb[off];
    kT[r * 260 + t] = kb[off];
    mT[r * 260 + t] = mb[off];
  }
  __syncthreads();

  float gqk = 0.f, gmm = 0.f, dq = 0.f, dk = 0.f;
  const float4* q4  = (const float4*)(qT + n * 260);
  const float4* k4  = (const float4*)(kT + m * 260);
  const float4* mn4 = (const float4*)(mT + n * 260);
  const float4* mm4 = (const float4*)(mT + m * 260);
  #pragma unroll 4
  for (int jq = 0; jq < 64; ++jq) {
    float4 a = q4[jq], b = k4[jq];
    gqk = fmaf(a.x, b.x, fmaf(a.y, b.y, fmaf(a.z, b.z, fmaf(a.w, b.w, gqk))));
    float4 cc = mn4[jq], d = mm4[jq];
    gmm = fmaf(cc.x, d.x, fmaf(cc.y, d.y, fmaf(cc.z, d.z, fmaf(cc.w, d.w, gmm))));
  }
  const float* qr = qT + n * 260;
  const float* kr = kT + n * 260;
  #pragma unroll
  for (int jj = 0; jj < 16; ++jj) {
    float qv = qr[m + 16 * jj]; dq = fmaf(qv, qv, dq);
    float kv = kr[m + 16 * jj]; dk = fmaf(kv, kv, dk);
  }
  #pragma unroll
  for (int off = 8; off; off >>= 1) {
    dq += __shfl_xor(dq, off, 16);
    dk += __shfl_xor(dk, off, 16);
  }

  float* pb = pbuf + (((size_t)lb * DIM + g) * 16 + c) * PSTRIDE;
  pb[t] = gqk;
  pb[256 + t] = gmm;
  if (m == 0) { pb[512 + n] = dq; pb[528 + n] = dk; }
}

// ---------------- K3b: reduce partials + softmax chain -> attn[16][16] ---------
// grid (96, nb), block 256
__global__ __launch_bounds__(256) void k_attn_fin(
    const float* __restrict__ pbuf, const float* __restrict__ tx,
    const float* __restrict__ tm, float* __restrict__ attnbuf) {
  int g = blockIdx.x;
  int lb = blockIdx.y;
  int h = g / CPH;
  int t = threadIdx.x;
  int n = t >> 4, m = t & 15;

  const float* pb = pbuf + ((size_t)lb * DIM + g) * 16 * PSTRIDE;
  float gqk = 0.f, gmm = 0.f, dq = 0.f, dk = 0.f;
  #pragma unroll
  for (int c = 0; c < 16; ++c) {
    const float* p = pb + c * PSTRIDE;
    gqk += p[t];
    gmm += p[256 + t];
    dq  += p[512 + n];
    dk  += p[528 + m];
  }

  float qn = fmaxf(sqrtf(dq), EPSN);
  float km = fmaxf(sqrtf(dk), EPSN);

  float ax = gqk / (qn * km) * tx[h];
  float r0 = ax;
  #pragma unroll
  for (int off = 8; off; off >>= 1) r0 = fmaxf(r0, __shfl_xor(r0, off, 16));
  float e0 = expf(ax - r0), es0 = e0;
  #pragma unroll
  for (int off = 8; off; off >>= 1) es0 += __shfl_xor(es0, off, 16);
  float attx = e0 / es0;

  float am = gmm * tm[h];
  float s2 = am * am;
  #pragma unroll
  for (int off = 8; off; off >>= 1) s2 += __shfl_xor(s2, off, 16);
  am = am / fmaxf(sqrtf(s2), EPSN);
  float r1 = am;
  #pragma unroll
  for (int off = 8; off; off >>= 1) r1 = fmaxf(r1, __shfl_xor(r1, off, 16));
  float e1 = expf(am - r1), es1 = e1;
  #pragma unroll
  for (int off = 8; off; off >>= 1) es1 += __shfl_xor(es1, off, 16);
  float attm = e1 / es1;

  float aa = attx + attm;
  float r2 = aa;
  #pragma unroll
  for (int off = 8; off; off >>= 1) r2 = fmaxf(r2, __shfl_xor(r2, off, 16));
  float e2 = expf(aa - r2), es2 = e2;
  #pragma unroll
  for (int off = 8; off; off >>= 1) es2 += __shfl_xor(es2, off, 16);

  attnbuf[(((size_t)lb * DIM + g) << 8) + t] = e2 / es2;
}

// ---------------- K4: out_blk = attn @ v, written un-blockified ----------------
// grid (64 (hh), 96 (g), nb), block 256
__global__ __launch_bounds__(256) void k_pv(
    const float* __restrict__ qkv2, const float* __restrict__ attnbuf,
    float* __restrict__ tout) {
  int hh = blockIdx.x;
  int g = blockIdx.y;
  int lb = blockIdx.z;
  int t = threadIdx.x;
  int ww = t & 63, grp = t >> 6;

  __shared__ float vt[16][64];
  __shared__ float at[16][16];

  const float* vb = qkv2 + ((size_t)lb * QKVC + 2 * DIM + g) * NPIX;
  #pragma unroll
  for (int jj = 0; jj < 4; ++jj) {
    int mm = jj * 4 + grp;
    vt[mm][ww] = vb[(size_t)(((mm >> 2) << 6) + hh) * WPIX + ((mm & 3) << 6) + ww];
  }
  at[t >> 4][t & 15] = attnbuf[(((size_t)lb * DIM + g) << 8) + t];
  __syncthreads();

  float* ob = tout + ((size_t)lb * DIM + g) * NPIX;
  #pragma unroll
  for (int jj = 0; jj < 4; ++jj) {
    int nn = jj * 4 + grp;
    float acc = 0.f;
    #pragma unroll
    for (int mm = 0; mm < 16; ++mm)
      acc = fmaf(at[nn][mm], vt[mm][ww], acc);
    ob[(size_t)(((nn >> 2) << 6) + hh) * WPIX + ((nn & 3) << 6) + ww] = acc;
  }
}

extern "C" void kernel_launch(void* const* d_in, const int* in_sizes, int n_in,
                              void* d_out, int out_size, void* d_ws, size_t ws_size,
                              hipStream_t stream) {
  const float* x      = (const float*)d_in[0];
  const float* mask   = (const float*)d_in[1];
  const float* w_qkv  = (const float*)d_in[2];
  const float* w_dw   = (const float*)d_in[3];
  const float* w_proj = (const float*)d_in[4];
  const float* tx     = (const float*)d_in[5];
  const float* tm     = (const float*)d_in[6];
  float* out = (float*)d_out;

  const size_t qkvBytes = (size_t)QKVC * NPIX * sizeof(float);  // 75.5 MB per batch
  const size_t attnBytesPerB = (size_t)DIM * 256 * sizeof(float);
  const size_t wBytes = (size_t)(2 * QKVC * DIM + 2 * DIM * DIM) * 2;  // 147456, 256-aligned

  int nb, npass;
  if (ws_size >= wBytes + 8 * qkvBytes + 4 * attnBytesPerB) { nb = 4; npass = 1; }
  else                                                      { nb = 1; npass = 4; }

  char* base = (char*)d_ws;
  unsigned short* wqh = (unsigned short*)base;
  unsigned short* wql = wqh + QKVC * DIM;
  unsigned short* wph = wql + QKVC * DIM;
  unsigned short* wpl = wph + DIM * DIM;

  float* qkv1 = (float*)(base + wBytes);                            // nb * qkvBytes
  float* qkv2 = (float*)(base + wBytes + (size_t)nb * qkvBytes);    // nb * qkvBytes
  float* attn = (float*)(base + wBytes + 2 * (size_t)nb * qkvBytes);
  float* tbuf = qkv1;  // alias: qkv1 dead after k_dw3x3
  float* pbuf = qkv1 + (size_t)nb * DIM * NPIX;  // past tbuf region

  dim3 blk(256);
  k_wprep<<<dim3((QKVC * DIM + 255) / 256), blk, 0, stream>>>(
      w_qkv, w_proj, wqh, wql, wph, wpl);

  for (int pass = 0; pass < npass; ++pass) {
    int b0 = pass * nb;
    const float* xb = x + (size_t)b0 * DIM * NPIX;
    k_gemm1x1<QKVC><<<dim3(NPIX / 64, nb), blk, 0, stream>>>(xb, wqh, wql, qkv1);
    k_dw3x3<<<dim3(NPIX / 1024, QKVC, nb), blk, 0, stream>>>(qkv1, w_dw, qkv2);
    k_attn_part<<<dim3(DIM, 16, nb), blk, 0, stream>>>(qkv2, mask, pbuf, b0);
    k_attn_fin<<<dim3(DIM, nb), blk, 0, stream>>>(pbuf, tx, tm, attn);
    k_pv<<<dim3(64, DIM, nb), blk, 0, stream>>>(qkv2, attn, tbuf);
    k_gemm1x1<DIM><<<dim3(NPIX / 64, nb), blk, 0, stream>>>(
        tbuf, wph, wpl, out + (size_t)b0 * DIM * NPIX);
  }
}

// Round 6
// 448.898 us; speedup vs baseline: 1.4426x; 1.2114x over previous
//
#include <hip/hip_runtime.h>
#include <math.h>

#define HPIX 256
#define WPIX 256
#define NPIX (HPIX * WPIX)
#define DIM 96
#define QKVC 288
#define NHEAD 8
#define CPH 12
#define EPSN 1e-12f
#define PSTRIDE 544  // per (b,g,chunk) partial record: 256 gqk + 256 gmm + 16 dq + 16 dk

typedef __attribute__((ext_vector_type(8))) short bf16x8;
typedef __attribute__((ext_vector_type(4))) float f32x4;

__device__ __forceinline__ unsigned short f2bf(float f) {
  unsigned u = __float_as_uint(f);
  u += 0x7FFF + ((u >> 16) & 1);  // RNE
  return (unsigned short)(u >> 16);
}
__device__ __forceinline__ float bf2f(unsigned short h) {
  return __uint_as_float((unsigned)h << 16);
}

// ---------------- K0: split weights into bf16 hi/lo (once per launch) --------
__global__ __launch_bounds__(256) void k_wprep(
    const float* __restrict__ wq, const float* __restrict__ wp,
    unsigned short* __restrict__ wqh, unsigned short* __restrict__ wql,
    unsigned short* __restrict__ wph, unsigned short* __restrict__ wpl) {
  int i = blockIdx.x * 256 + threadIdx.x;
  if (i < QKVC * DIM) {
    float v = wq[i];
    unsigned short h = f2bf(v);
    wqh[i] = h;
    wql[i] = f2bf(v - bf2f(h));
  }
  if (i < DIM * DIM) {
    float v = wp[i];
    unsigned short h = f2bf(v);
    wph[i] = h;
    wpl[i] = f2bf(v - bf2f(h));
  }
}

// ---------------- K1/K5: 1x1 conv MFMA GEMM, full-OC per 64-px block ---------
// out[oc][p] = sum_ic w[oc][ic] x[ic][p].  grid (NPIX/64, nbz), block 256
// OutT = ushort (bf16 store) or float.
template<int OC, typename OutT>
__global__ __launch_bounds__(256) void k_gemm1x1(
    const float* __restrict__ xin,
    const unsigned short* __restrict__ wh, const unsigned short* __restrict__ wl,
    OutT* __restrict__ out) {
  __shared__ __align__(16) unsigned short xhi[64 * 128];
  __shared__ __align__(16) unsigned short xlo[64 * 128];
  int t = threadIdx.x;
  int p0 = blockIdx.x * 64;
  const float* xb = xin + (size_t)blockIdx.y * DIM * NPIX + p0;

  if (t < 192) {
    int kg = t >> 4;   // 0..11 (8-k group)
    int f4 = t & 15;   // float4 column
    float4 v[8];
    #pragma unroll
    for (int i = 0; i < 8; ++i)
      v[i] = *(const float4*)(xb + (size_t)(kg * 8 + i) * NPIX + f4 * 4);
    #pragma unroll
    for (int c = 0; c < 4; ++c) {
      int px = f4 * 4 + c;
      int u = kg ^ ((px & 7) ^ ((px >> 3) & 7));
      bf16x8 hv, lv;
      #pragma unroll
      for (int i = 0; i < 8; ++i) {
        float vv = ((const float*)&v[i])[c];
        unsigned short h = f2bf(vv);
        hv[i] = (short)h;
        lv[i] = (short)f2bf(vv - bf2f(h));
      }
      *(bf16x8*)&xhi[px * 128 + u * 8] = hv;
      *(bf16x8*)&xlo[px * 128 + u * 8] = lv;
    }
  }
  __syncthreads();

  int lane = t & 63, wv = t >> 6;
  int r16 = lane & 15, kg8 = lane >> 4;
  int px = wv * 16 + r16;
  int swz = (px & 7) ^ ((px >> 3) & 7);

  bf16x8 bh[3], bl[3];
  #pragma unroll
  for (int ks = 0; ks < 3; ++ks) {
    int u = (ks * 4 + kg8) ^ swz;
    bh[ks] = *(const bf16x8*)&xhi[px * 128 + u * 8];
    bl[ks] = *(const bf16x8*)&xlo[px * 128 + u * 8];
  }

  f32x4 acc[OC / 16];
  #pragma unroll
  for (int mi = 0; mi < OC / 16; ++mi) acc[mi] = (f32x4){0.f, 0.f, 0.f, 0.f};

  #pragma unroll
  for (int mi = 0; mi < OC / 16; ++mi) {
    #pragma unroll
    for (int ks = 0; ks < 3; ++ks) {
      size_t woff = (size_t)(mi * 16 + r16) * DIM + ks * 32 + kg8 * 8;
      bf16x8 ah = *(const bf16x8*)(wh + woff);
      bf16x8 al = *(const bf16x8*)(wl + woff);
      acc[mi] = __builtin_amdgcn_mfma_f32_16x16x32_bf16(ah, bh[ks], acc[mi], 0, 0, 0);
      acc[mi] = __builtin_amdgcn_mfma_f32_16x16x32_bf16(ah, bl[ks], acc[mi], 0, 0, 0);
      acc[mi] = __builtin_amdgcn_mfma_f32_16x16x32_bf16(al, bh[ks], acc[mi], 0, 0, 0);
    }
  }

  OutT* op = out + (size_t)blockIdx.y * OC * NPIX + p0 + wv * 16 + r16;
  #pragma unroll
  for (int mi = 0; mi < OC / 16; ++mi) {
    #pragma unroll
    for (int j = 0; j < 4; ++j) {
      int o = mi * 16 + kg8 * 4 + j;  // C/D: row=(lane>>4)*4+j, col=lane&15
      float v = acc[mi][j];
      if constexpr (sizeof(OutT) == 2) op[(size_t)o * NPIX] = f2bf(v);
      else                             op[(size_t)o * NPIX] = v;
    }
  }
}

// ---------------- K2: depthwise 3x3 on bf16 input, split outputs -------------
// grid (NPIX/1024, 288) per batch, block 256.
// ch<192 -> bf16 q/k planes; ch>=192 -> fp32 v planes.
__global__ __launch_bounds__(256) void k_dw3x3_bf(
    const unsigned short* __restrict__ in, const float* __restrict__ w,
    unsigned short* __restrict__ qkout, float* __restrict__ vout) {
  int t = threadIdx.x;
  int p0 = (blockIdx.x * 256 + t) * 4;
  int ch = blockIdx.y;
  const unsigned short* plane = in + (size_t)ch * NPIX;
  int y = p0 >> 8, x0 = p0 & 255;
  const float* wc = w + ch * 9;
  float a0 = 0.f, a1 = 0.f, a2 = 0.f, a3 = 0.f;
  #pragma unroll
  for (int dy = -1; dy <= 1; ++dy) {
    int yy = y + dy;
    if (yy < 0 || yy >= HPIX) continue;
    const unsigned short* row = plane + (size_t)yy * WPIX + x0;
    ushort4 c4 = *(const ushort4*)row;
    float cx = bf2f(c4.x), cy = bf2f(c4.y), cz = bf2f(c4.z), cw = bf2f(c4.w);
    float l = (x0 > 0) ? bf2f(row[-1]) : 0.f;
    float r = (x0 < 252) ? bf2f(row[4]) : 0.f;
    float w0 = wc[(dy + 1) * 3], w1 = wc[(dy + 1) * 3 + 1], w2 = wc[(dy + 1) * 3 + 2];
    a0 = fmaf(w0, l,  fmaf(w1, cx, fmaf(w2, cy, a0)));
    a1 = fmaf(w0, cx, fmaf(w1, cy, fmaf(w2, cz, a1)));
    a2 = fmaf(w0, cy, fmaf(w1, cz, fmaf(w2, cw, a2)));
    a3 = fmaf(w0, cz, fmaf(w1, cw, fmaf(w2, r,  a3)));
  }
  if (ch < 192) {
    ushort4 o = {f2bf(a0), f2bf(a1), f2bf(a2), f2bf(a3)};
    *(ushort4*)(qkout + (size_t)ch * NPIX + p0) = o;
  } else {
    *(float4*)(vout + (size_t)(ch - 192) * NPIX + p0) = make_float4(a0, a1, a2, a3);
  }
}

// ---------------- K3a: per-(b,g,chunk) partial grams + row norms -------------
// grid (96, 16, 4), block 256. q,k bf16; mask fp32.
__global__ __launch_bounds__(256) void k_attn_part(
    const unsigned short* __restrict__ qkbuf, const float* __restrict__ mask,
    float* __restrict__ pbuf) {
  int g = blockIdx.x;
  int c = blockIdx.y;
  int lb = blockIdx.z;
  int t = threadIdx.x;
  int n = t >> 4, m = t & 15;

  __shared__ float qT[16 * 260];
  __shared__ float kT[16 * 260];
  __shared__ float mT[16 * 260];

  const unsigned short* qb = qkbuf + ((size_t)lb * 192 + g) * NPIX;
  const unsigned short* kb = qkbuf + ((size_t)lb * 192 + 96 + g) * NPIX;
  const float* mb = mask + ((size_t)lb * DIM + g) * NPIX;

  int hh0 = (c << 2) + (t >> 6);
  int w0 = t & 63;
  #pragma unroll
  for (int r = 0; r < 16; ++r) {  // r = spatial block h1*4+w1
    size_t off = (size_t)(((r >> 2) << 6) + hh0) * WPIX + ((r & 3) << 6) + w0;
    qT[r * 260 + t] = bf2f(qb[off]);
    kT[r * 260 + t] = bf2f(kb[off]);
    mT[r * 260 + t] = mb[off];
  }
  __syncthreads();

  float gqk = 0.f, gmm = 0.f, dq = 0.f, dk = 0.f;
  const float4* q4  = (const float4*)(qT + n * 260);
  const float4* k4  = (const float4*)(kT + m * 260);
  const float4* mn4 = (const float4*)(mT + n * 260);
  const float4* mm4 = (const float4*)(mT + m * 260);
  #pragma unroll 4
  for (int jq = 0; jq < 64; ++jq) {
    float4 a = q4[jq], b = k4[jq];
    gqk = fmaf(a.x, b.x, fmaf(a.y, b.y, fmaf(a.z, b.z, fmaf(a.w, b.w, gqk))));
    float4 cc = mn4[jq], d = mm4[jq];
    gmm = fmaf(cc.x, d.x, fmaf(cc.y, d.y, fmaf(cc.z, d.z, fmaf(cc.w, d.w, gmm))));
  }
  const float* qr = qT + n * 260;
  const float* kr = kT + n * 260;
  #pragma unroll
  for (int jj = 0; jj < 16; ++jj) {
    float qv = qr[m + 16 * jj]; dq = fmaf(qv, qv, dq);
    float kv = kr[m + 16 * jj]; dk = fmaf(kv, kv, dk);
  }
  #pragma unroll
  for (int off = 8; off; off >>= 1) {
    dq += __shfl_xor(dq, off, 16);
    dk += __shfl_xor(dk, off, 16);
  }

  float* pb = pbuf + (((size_t)lb * DIM + g) * 16 + c) * PSTRIDE;
  pb[t] = gqk;
  pb[256 + t] = gmm;
  if (m == 0) { pb[512 + n] = dq; pb[528 + n] = dk; }
}

// ---------------- K3b: reduce partials + softmax chain -> attn[16][16] -------
// grid (96, 4), block 256
__global__ __launch_bounds__(256) void k_attn_fin(
    const float* __restrict__ pbuf, const float* __restrict__ tx,
    const float* __restrict__ tm, float* __restrict__ attnbuf) {
  int g = blockIdx.x;
  int lb = blockIdx.y;
  int h = g / CPH;
  int t = threadIdx.x;
  int n = t >> 4, m = t & 15;

  const float* pb = pbuf + ((size_t)lb * DIM + g) * 16 * PSTRIDE;
  float gqk = 0.f, gmm = 0.f, dq = 0.f, dk = 0.f;
  #pragma unroll
  for (int c = 0; c < 16; ++c) {
    const float* p = pb + c * PSTRIDE;
    gqk += p[t];
    gmm += p[256 + t];
    dq  += p[512 + n];
    dk  += p[528 + m];
  }

  float qn = fmaxf(sqrtf(dq), EPSN);
  float km = fmaxf(sqrtf(dk), EPSN);

  float ax = gqk / (qn * km) * tx[h];
  float r0 = ax;
  #pragma unroll
  for (int off = 8; off; off >>= 1) r0 = fmaxf(r0, __shfl_xor(r0, off, 16));
  float e0 = expf(ax - r0), es0 = e0;
  #pragma unroll
  for (int off = 8; off; off >>= 1) es0 += __shfl_xor(es0, off, 16);
  float attx = e0 / es0;

  float am = gmm * tm[h];
  float s2 = am * am;
  #pragma unroll
  for (int off = 8; off; off >>= 1) s2 += __shfl_xor(s2, off, 16);
  am = am / fmaxf(sqrtf(s2), EPSN);
  float r1 = am;
  #pragma unroll
  for (int off = 8; off; off >>= 1) r1 = fmaxf(r1, __shfl_xor(r1, off, 16));
  float e1 = expf(am - r1), es1 = e1;
  #pragma unroll
  for (int off = 8; off; off >>= 1) es1 += __shfl_xor(es1, off, 16);
  float attm = e1 / es1;

  float aa = attx + attm;
  float r2 = aa;
  #pragma unroll
  for (int off = 8; off; off >>= 1) r2 = fmaxf(r2, __shfl_xor(r2, off, 16));
  float e2 = expf(aa - r2), es2 = e2;
  #pragma unroll
  for (int off = 8; off; off >>= 1) es2 += __shfl_xor(es2, off, 16);

  attnbuf[(((size_t)lb * DIM + g) << 8) + t] = e2 / es2;
}

// ---------------- K4: out_blk = attn @ v, written un-blockified --------------
// grid (64 (hh), 96 (g), 4), block 256
__global__ __launch_bounds__(256) void k_pv(
    const float* __restrict__ vbuf, const float* __restrict__ attnbuf,
    float* __restrict__ tout) {
  int hh = blockIdx.x;
  int g = blockIdx.y;
  int lb = blockIdx.z;
  int t = threadIdx.x;
  int ww = t & 63, grp = t >> 6;

  __shared__ float vt[16][64];
  __shared__ float at[16][16];

  const float* vb = vbuf + ((size_t)lb * DIM + g) * NPIX;
  #pragma unroll
  for (int jj = 0; jj < 4; ++jj) {
    int mm = jj * 4 + grp;
    vt[mm][ww] = vb[(size_t)(((mm >> 2) << 6) + hh) * WPIX + ((mm & 3) << 6) + ww];
  }
  at[t >> 4][t & 15] = attnbuf[(((size_t)lb * DIM + g) << 8) + t];
  __syncthreads();

  float* ob = tout + ((size_t)lb * DIM + g) * NPIX;
  #pragma unroll
  for (int jj = 0; jj < 4; ++jj) {
    int nn = jj * 4 + grp;
    float acc = 0.f;
    #pragma unroll
    for (int mm = 0; mm < 16; ++mm)
      acc = fmaf(at[nn][mm], vt[mm][ww], acc);
    ob[(size_t)(((nn >> 2) << 6) + hh) * WPIX + ((nn & 3) << 6) + ww] = acc;
  }
}

extern "C" void kernel_launch(void* const* d_in, const int* in_sizes, int n_in,
                              void* d_out, int out_size, void* d_ws, size_t ws_size,
                              hipStream_t stream) {
  const float* x      = (const float*)d_in[0];
  const float* mask   = (const float*)d_in[1];
  const float* w_qkv  = (const float*)d_in[2];
  const float* w_dw   = (const float*)d_in[3];
  const float* w_proj = (const float*)d_in[4];
  const float* tx     = (const float*)d_in[5];
  const float* tm     = (const float*)d_in[6];
  float* out = (float*)d_out;

  // ws layout (253 MB total; ws is ~402 MB):
  //  w hi/lo (147456 B) | qkv1bf (37.7 MB, per-batch) | qkbuf bf16 4x192 planes
  //  (100.7 MB, aliased by tbuf f32 later) | vbuf f32 4x96 (100.7 MB)
  //  | attn (0.4 MB) | pbuf (13.4 MB)
  char* base = (char*)d_ws;
  unsigned short* wqh = (unsigned short*)base;
  unsigned short* wql = wqh + QKVC * DIM;
  unsigned short* wph = wql + QKVC * DIM;
  unsigned short* wpl = wph + DIM * DIM;
  char* p = base + (size_t)(2 * QKVC * DIM + 2 * DIM * DIM) * 2;

  unsigned short* qkv1bf = (unsigned short*)p;           p += (size_t)QKVC * NPIX * 2;
  unsigned short* qkbuf  = (unsigned short*)p;           // 4*192*NPIX shorts
  float*          tbuf   = (float*)p;                    // alias: 4*96*NPIX floats (same bytes)
  p += (size_t)4 * 192 * NPIX * 2;
  float* vbuf = (float*)p;                               p += (size_t)4 * DIM * NPIX * 4;
  float* attn = (float*)p;                               p += (size_t)4 * DIM * 256 * 4;
  float* pbuf = (float*)p;

  dim3 blk(256);
  k_wprep<<<dim3((QKVC * DIM + 255) / 256), blk, 0, stream>>>(
      w_qkv, w_proj, wqh, wql, wph, wpl);

  for (int b = 0; b < 4; ++b) {
    const float* xb = x + (size_t)b * DIM * NPIX;
    k_gemm1x1<QKVC, unsigned short><<<dim3(NPIX / 64, 1), blk, 0, stream>>>(
        xb, wqh, wql, qkv1bf);
    k_dw3x3_bf<<<dim3(NPIX / 1024, QKVC), blk, 0, stream>>>(
        qkv1bf, w_dw, qkbuf + (size_t)b * 192 * NPIX, vbuf + (size_t)b * DIM * NPIX);
  }
  k_attn_part<<<dim3(DIM, 16, 4), blk, 0, stream>>>(qkbuf, mask, pbuf);
  k_attn_fin<<<dim3(DIM, 4), blk, 0, stream>>>(pbuf, tx, tm, attn);
  k_pv<<<dim3(64, DIM, 4), blk, 0, stream>>>(vbuf, attn, tbuf);
  k_gemm1x1<DIM, float><<<dim3(NPIX / 64, 4), blk, 0, stream>>>(
      tbuf, wph, wpl, out);
}

// Round 7
// 401.189 us; speedup vs baseline: 1.6141x; 1.1189x over previous
//
#include <hip/hip_runtime.h>
#include <math.h>

#define HPIX 256
#define WPIX 256
#define NPIX (HPIX * WPIX)
#define DIM 96
#define QKVC 288
#define NHEAD 8
#define CPH 12
#define EPSN 1e-12f
#define PSTRIDE 544  // per (b,g,chunk) partial record: 256 gqk + 256 gmm + 16 dq + 16 dk

typedef __attribute__((ext_vector_type(8))) short bf16x8;
typedef __attribute__((ext_vector_type(4))) float f32x4;

__device__ __forceinline__ unsigned short f2bf(float f) {
  unsigned u = __float_as_uint(f);
  u += 0x7FFF + ((u >> 16) & 1);  // RNE
  return (unsigned short)(u >> 16);
}
__device__ __forceinline__ float bf2f(unsigned short h) {
  return __uint_as_float((unsigned)h << 16);
}

// ---------------- K0: split weights into bf16 hi/lo (once per launch) --------
__global__ __launch_bounds__(256) void k_wprep(
    const float* __restrict__ wq, const float* __restrict__ wp,
    unsigned short* __restrict__ wqh, unsigned short* __restrict__ wql,
    unsigned short* __restrict__ wph, unsigned short* __restrict__ wpl) {
  int i = blockIdx.x * 256 + threadIdx.x;
  if (i < QKVC * DIM) {
    float v = wq[i];
    unsigned short h = f2bf(v);
    wqh[i] = h;
    wql[i] = f2bf(v - bf2f(h));
  }
  if (i < DIM * DIM) {
    float v = wp[i];
    unsigned short h = f2bf(v);
    wph[i] = h;
    wpl[i] = f2bf(v - bf2f(h));
  }
}

// ---------------- K1/K5: 1x1 conv MFMA GEMM, full-OC per 64-px block ---------
// out[oc][p] = sum_ic w[oc][ic] x[ic][p].  grid (NPIX/64, nbz), block 256
template<int OC, typename OutT>
__global__ __launch_bounds__(256) void k_gemm1x1(
    const float* __restrict__ xin,
    const unsigned short* __restrict__ wh, const unsigned short* __restrict__ wl,
    OutT* __restrict__ out) {
  __shared__ __align__(16) unsigned short xhi[64 * 128];
  __shared__ __align__(16) unsigned short xlo[64 * 128];
  int t = threadIdx.x;
  int p0 = blockIdx.x * 64;
  const float* xb = xin + (size_t)blockIdx.y * DIM * NPIX + p0;

  if (t < 192) {
    int kg = t >> 4;   // 0..11 (8-k group)
    int f4 = t & 15;   // float4 column
    float4 v[8];
    #pragma unroll
    for (int i = 0; i < 8; ++i)
      v[i] = *(const float4*)(xb + (size_t)(kg * 8 + i) * NPIX + f4 * 4);
    #pragma unroll
    for (int c = 0; c < 4; ++c) {
      int px = f4 * 4 + c;
      int u = kg ^ ((px & 7) ^ ((px >> 3) & 7));
      bf16x8 hv, lv;
      #pragma unroll
      for (int i = 0; i < 8; ++i) {
        float vv = ((const float*)&v[i])[c];
        unsigned short h = f2bf(vv);
        hv[i] = (short)h;
        lv[i] = (short)f2bf(vv - bf2f(h));
      }
      *(bf16x8*)&xhi[px * 128 + u * 8] = hv;
      *(bf16x8*)&xlo[px * 128 + u * 8] = lv;
    }
  }
  __syncthreads();

  int lane = t & 63, wv = t >> 6;
  int r16 = lane & 15, kg8 = lane >> 4;
  int px = wv * 16 + r16;
  int swz = (px & 7) ^ ((px >> 3) & 7);

  bf16x8 bh[3], bl[3];
  #pragma unroll
  for (int ks = 0; ks < 3; ++ks) {
    int u = (ks * 4 + kg8) ^ swz;
    bh[ks] = *(const bf16x8*)&xhi[px * 128 + u * 8];
    bl[ks] = *(const bf16x8*)&xlo[px * 128 + u * 8];
  }

  f32x4 acc[OC / 16];
  #pragma unroll
  for (int mi = 0; mi < OC / 16; ++mi) acc[mi] = (f32x4){0.f, 0.f, 0.f, 0.f};

  #pragma unroll
  for (int mi = 0; mi < OC / 16; ++mi) {
    #pragma unroll
    for (int ks = 0; ks < 3; ++ks) {
      size_t woff = (size_t)(mi * 16 + r16) * DIM + ks * 32 + kg8 * 8;
      bf16x8 ah = *(const bf16x8*)(wh + woff);
      bf16x8 al = *(const bf16x8*)(wl + woff);
      acc[mi] = __builtin_amdgcn_mfma_f32_16x16x32_bf16(ah, bh[ks], acc[mi], 0, 0, 0);
      acc[mi] = __builtin_amdgcn_mfma_f32_16x16x32_bf16(ah, bl[ks], acc[mi], 0, 0, 0);
      acc[mi] = __builtin_amdgcn_mfma_f32_16x16x32_bf16(al, bh[ks], acc[mi], 0, 0, 0);
    }
  }

  OutT* op = out + (size_t)blockIdx.y * OC * NPIX + p0 + wv * 16 + r16;
  #pragma unroll
  for (int mi = 0; mi < OC / 16; ++mi) {
    #pragma unroll
    for (int j = 0; j < 4; ++j) {
      int o = mi * 16 + kg8 * 4 + j;  // C/D: row=(lane>>4)*4+j, col=lane&15
      float v = acc[mi][j];
      if constexpr (sizeof(OutT) == 2) op[(size_t)o * NPIX] = f2bf(v);
      else                             op[(size_t)o * NPIX] = v;
    }
  }
}

// ---------------- K2: depthwise 3x3 on bf16 input, split bf16 outputs --------
// grid (NPIX/1024, 288, nb), block 256. ch<192 -> qk planes; ch>=192 -> v planes
__global__ __launch_bounds__(256) void k_dw3x3_bf(
    const unsigned short* __restrict__ in, const float* __restrict__ w,
    unsigned short* __restrict__ qkout, unsigned short* __restrict__ vout) {
  int t = threadIdx.x;
  int p0 = (blockIdx.x * 256 + t) * 4;
  int ch = blockIdx.y;
  int b = blockIdx.z;
  const unsigned short* plane = in + ((size_t)b * QKVC + ch) * NPIX;
  int y = p0 >> 8, x0 = p0 & 255;
  const float* wc = w + ch * 9;
  float a0 = 0.f, a1 = 0.f, a2 = 0.f, a3 = 0.f;
  #pragma unroll
  for (int dy = -1; dy <= 1; ++dy) {
    int yy = y + dy;
    if (yy < 0 || yy >= HPIX) continue;
    const unsigned short* row = plane + (size_t)yy * WPIX + x0;
    ushort4 c4 = *(const ushort4*)row;
    float cx = bf2f(c4.x), cy = bf2f(c4.y), cz = bf2f(c4.z), cw = bf2f(c4.w);
    float l = (x0 > 0) ? bf2f(row[-1]) : 0.f;
    float r = (x0 < 252) ? bf2f(row[4]) : 0.f;
    float w0 = wc[(dy + 1) * 3], w1 = wc[(dy + 1) * 3 + 1], w2 = wc[(dy + 1) * 3 + 2];
    a0 = fmaf(w0, l,  fmaf(w1, cx, fmaf(w2, cy, a0)));
    a1 = fmaf(w0, cx, fmaf(w1, cy, fmaf(w2, cz, a1)));
    a2 = fmaf(w0, cy, fmaf(w1, cz, fmaf(w2, cw, a2)));
    a3 = fmaf(w0, cz, fmaf(w1, cw, fmaf(w2, r,  a3)));
  }
  ushort4 o = {f2bf(a0), f2bf(a1), f2bf(a2), f2bf(a3)};
  if (ch < 192) *(ushort4*)(qkout + ((size_t)b * 192 + ch) * NPIX + p0) = o;
  else          *(ushort4*)(vout + ((size_t)b * DIM + ch - 192) * NPIX + p0) = o;
}

// ---------------- K3a: MFMA partial grams + row norms, 1 wave/block ----------
// grid (96, 16, nb), block 64. Wave covers s in [cb*256, cb*256+256).
// A=q row-frags, B=k row-frags load with IDENTICAL per-lane indexing (verified
// pattern from k_gemm1x1). Mask gram uses the same fragment on A and B.
__global__ __launch_bounds__(64) void k_attn_part(
    const unsigned short* __restrict__ qkbuf, const float* __restrict__ mask,
    float* __restrict__ pbuf) {
  int g = blockIdx.x, cb = blockIdx.y, lb = blockIdx.z;
  int lane = threadIdx.x;
  int r16 = lane & 15, kg8 = lane >> 4;

  const unsigned short* qb = qkbuf + ((size_t)lb * 192 + g) * NPIX;
  const unsigned short* kb = qkbuf + ((size_t)lb * 192 + 96 + g) * NPIX;
  const float* mb = mask + ((size_t)lb * DIM + g) * NPIX;

  // spatial-block row base for row r16: (h1*64)*256 + w1*64
  int rbase = ((r16 >> 2) << 6) * WPIX + ((r16 & 3) << 6);

  f32x4 aqk = {0.f, 0.f, 0.f, 0.f}, amm = {0.f, 0.f, 0.f, 0.f};
  float dq = 0.f, dk = 0.f;

  #pragma unroll
  for (int ks = 0; ks < 8; ++ks) {
    int s = cb * 256 + ks * 32 + kg8 * 8;       // 8-aligned, within one hh row
    int off = rbase + (s >> 6) * WPIX + (s & 63);
    bf16x8 qf = *(const bf16x8*)(qb + off);
    bf16x8 kf = *(const bf16x8*)(kb + off);
    float4 m0 = *(const float4*)(mb + off);
    float4 m1 = *(const float4*)(mb + off + 4);
    bf16x8 mf;
    mf[0] = (short)f2bf(m0.x); mf[1] = (short)f2bf(m0.y);
    mf[2] = (short)f2bf(m0.z); mf[3] = (short)f2bf(m0.w);
    mf[4] = (short)f2bf(m1.x); mf[5] = (short)f2bf(m1.y);
    mf[6] = (short)f2bf(m1.z); mf[7] = (short)f2bf(m1.w);
    aqk = __builtin_amdgcn_mfma_f32_16x16x32_bf16(qf, kf, aqk, 0, 0, 0);
    amm = __builtin_amdgcn_mfma_f32_16x16x32_bf16(mf, mf, amm, 0, 0, 0);
    #pragma unroll
    for (int i = 0; i < 8; ++i) {
      float qv = bf2f((unsigned short)qf[i]); dq = fmaf(qv, qv, dq);
      float kv = bf2f((unsigned short)kf[i]); dk = fmaf(kv, kv, dk);
    }
  }
  // reduce diag over the 4 k-groups (lanes differing in bits 4..5)
  dq += __shfl_xor(dq, 16); dq += __shfl_xor(dq, 32);
  dk += __shfl_xor(dk, 16); dk += __shfl_xor(dk, 32);

  float* pb = pbuf + (((size_t)lb * DIM + g) * 16 + cb) * PSTRIDE;
  #pragma unroll
  for (int j = 0; j < 4; ++j) {
    int n = kg8 * 4 + j;            // C/D row = (lane>>4)*4+j
    pb[n * 16 + r16] = aqk[j];      // col = lane&15
    pb[256 + n * 16 + r16] = amm[j];
  }
  if (lane < 16) { pb[512 + r16] = dq; pb[528 + r16] = dk; }
}

// ---------------- K3b: reduce partials + softmax chain -> attn[16][16] -------
// grid (96, nb), block 256
__global__ __launch_bounds__(256) void k_attn_fin(
    const float* __restrict__ pbuf, const float* __restrict__ tx,
    const float* __restrict__ tm, float* __restrict__ attnbuf) {
  int g = blockIdx.x;
  int lb = blockIdx.y;
  int h = g / CPH;
  int t = threadIdx.x;
  int n = t >> 4, m = t & 15;

  const float* pb = pbuf + ((size_t)lb * DIM + g) * 16 * PSTRIDE;
  float gqk = 0.f, gmm = 0.f, dq = 0.f, dk = 0.f;
  #pragma unroll
  for (int c = 0; c < 16; ++c) {
    const float* p = pb + c * PSTRIDE;
    gqk += p[t];
    gmm += p[256 + t];
    dq  += p[512 + n];
    dk  += p[528 + m];
  }

  float qn = fmaxf(sqrtf(dq), EPSN);
  float km = fmaxf(sqrtf(dk), EPSN);

  float ax = gqk / (qn * km) * tx[h];
  float r0 = ax;
  #pragma unroll
  for (int off = 8; off; off >>= 1) r0 = fmaxf(r0, __shfl_xor(r0, off, 16));
  float e0 = expf(ax - r0), es0 = e0;
  #pragma unroll
  for (int off = 8; off; off >>= 1) es0 += __shfl_xor(es0, off, 16);
  float attx = e0 / es0;

  float am = gmm * tm[h];
  float s2 = am * am;
  #pragma unroll
  for (int off = 8; off; off >>= 1) s2 += __shfl_xor(s2, off, 16);
  am = am / fmaxf(sqrtf(s2), EPSN);
  float r1 = am;
  #pragma unroll
  for (int off = 8; off; off >>= 1) r1 = fmaxf(r1, __shfl_xor(r1, off, 16));
  float e1 = expf(am - r1), es1 = e1;
  #pragma unroll
  for (int off = 8; off; off >>= 1) es1 += __shfl_xor(es1, off, 16);
  float attm = e1 / es1;

  float aa = attx + attm;
  float r2 = aa;
  #pragma unroll
  for (int off = 8; off; off >>= 1) r2 = fmaxf(r2, __shfl_xor(r2, off, 16));
  float e2 = expf(aa - r2), es2 = e2;
  #pragma unroll
  for (int off = 8; off; off >>= 1) es2 += __shfl_xor(es2, off, 16);

  attnbuf[(((size_t)lb * DIM + g) << 8) + t] = e2 / es2;
}

// ---------------- K4: out_blk = attn @ v (bf16 v), written un-blockified -----
// grid (64 (hh), 96 (g), nb), block 256
__global__ __launch_bounds__(256) void k_pv(
    const unsigned short* __restrict__ vbuf, const float* __restrict__ attnbuf,
    float* __restrict__ tout) {
  int hh = blockIdx.x;
  int g = blockIdx.y;
  int lb = blockIdx.z;
  int t = threadIdx.x;
  int ww = t & 63, grp = t >> 6;

  __shared__ float vt[16][64];
  __shared__ float at[16][16];

  const unsigned short* vb = vbuf + ((size_t)lb * DIM + g) * NPIX;
  #pragma unroll
  for (int jj = 0; jj < 4; ++jj) {
    int mm = jj * 4 + grp;
    vt[mm][ww] = bf2f(vb[(size_t)(((mm >> 2) << 6) + hh) * WPIX + ((mm & 3) << 6) + ww]);
  }
  at[t >> 4][t & 15] = attnbuf[(((size_t)lb * DIM + g) << 8) + t];
  __syncthreads();

  float* ob = tout + ((size_t)lb * DIM + g) * NPIX;
  #pragma unroll
  for (int jj = 0; jj < 4; ++jj) {
    int nn = jj * 4 + grp;
    float acc = 0.f;
    #pragma unroll
    for (int mm = 0; mm < 16; ++mm)
      acc = fmaf(at[nn][mm], vt[mm][ww], acc);
    ob[(size_t)(((nn >> 2) << 6) + hh) * WPIX + ((nn & 3) << 6) + ww] = acc;
  }
}

extern "C" void kernel_launch(void* const* d_in, const int* in_sizes, int n_in,
                              void* d_out, int out_size, void* d_ws, size_t ws_size,
                              hipStream_t stream) {
  const float* x      = (const float*)d_in[0];
  const float* mask   = (const float*)d_in[1];
  const float* w_qkv  = (const float*)d_in[2];
  const float* w_dw   = (const float*)d_in[3];
  const float* w_proj = (const float*)d_in[4];
  const float* tx     = (const float*)d_in[5];
  const float* tm     = (const float*)d_in[6];
  float* out = (float*)d_out;

  const size_t wB     = (size_t)(2 * QKVC * DIM + 2 * DIM * DIM) * 2;  // 147456
  const size_t qkv1B  = (size_t)QKVC * NPIX * 2;   // 37.75 MB (>= tbuf 25.2 MB)
  const size_t qkB    = (size_t)192 * NPIX * 2;    // 25.2 MB
  const size_t vB     = (size_t)DIM * NPIX * 2;    // 12.6 MB
  const size_t atB    = (size_t)DIM * 256 * 4;
  const size_t pbB    = (size_t)DIM * 16 * PSTRIDE * 4;
  const size_t perB   = qkv1B + qkB + vB + atB + pbB;

  int nb = (ws_size >= wB + 4 * perB) ? 4 : 1;
  int npass = 4 / nb;

  char* base = (char*)d_ws;
  unsigned short* wqh = (unsigned short*)base;
  unsigned short* wql = wqh + QKVC * DIM;
  unsigned short* wph = wql + QKVC * DIM;
  unsigned short* wpl = wph + DIM * DIM;
  char* p = base + wB;
  unsigned short* qkv1bf = (unsigned short*)p;  p += (size_t)nb * qkv1B;
  float*          tbuf   = (float*)qkv1bf;      // alias: dead after dw
  unsigned short* qkbuf  = (unsigned short*)p;  p += (size_t)nb * qkB;
  unsigned short* vbuf   = (unsigned short*)p;  p += (size_t)nb * vB;
  float*          attn   = (float*)p;           p += (size_t)nb * atB;
  float*          pbuf   = (float*)p;

  dim3 blk(256);
  k_wprep<<<dim3((QKVC * DIM + 255) / 256), blk, 0, stream>>>(
      w_qkv, w_proj, wqh, wql, wph, wpl);

  for (int pass = 0; pass < npass; ++pass) {
    int b0 = pass * nb;
    k_gemm1x1<QKVC, unsigned short><<<dim3(NPIX / 64, nb), blk, 0, stream>>>(
        x + (size_t)b0 * DIM * NPIX, wqh, wql, qkv1bf);
    k_dw3x3_bf<<<dim3(NPIX / 1024, QKVC, nb), blk, 0, stream>>>(
        qkv1bf, w_dw, qkbuf, vbuf);
    k_attn_part<<<dim3(DIM, 16, nb), dim3(64), 0, stream>>>(
        qkbuf, mask + (size_t)b0 * DIM * NPIX, pbuf);
    k_attn_fin<<<dim3(DIM, nb), blk, 0, stream>>>(pbuf, tx, tm, attn);
    k_pv<<<dim3(64, DIM, nb), blk, 0, stream>>>(vbuf, attn, tbuf);
    k_gemm1x1<DIM, float><<<dim3(NPIX / 64, nb), blk, 0, stream>>>(
        tbuf, wph, wpl, out + (size_t)b0 * DIM * NPIX);
  }
}

// Round 8
// 360.154 us; speedup vs baseline: 1.7980x; 1.1139x over previous
//
#include <hip/hip_runtime.h>
#include <math.h>

#define HPIX 256
#define WPIX 256
#define NPIX (HPIX * WPIX)
#define DIM 96
#define QKVC 288
#define NHEAD 8
#define CPH 12
#define EPSN 1e-12f
#define PSTRIDE 544  // per (b,g,chunk) partial record: 256 gqk + 256 gmm + 16 dq + 16 dk

typedef __attribute__((ext_vector_type(8))) short bf16x8;
typedef __attribute__((ext_vector_type(4))) float f32x4;

__device__ __forceinline__ unsigned short f2bf(float f) {
  unsigned u = __float_as_uint(f);
  u += 0x7FFF + ((u >> 16) & 1);  // RNE
  return (unsigned short)(u >> 16);
}
__device__ __forceinline__ float bf2f(unsigned short h) {
  return __uint_as_float((unsigned)h << 16);
}

// ---------------- K0: split weights into bf16 hi/lo (once per launch) --------
__global__ __launch_bounds__(256) void k_wprep(
    const float* __restrict__ wq, const float* __restrict__ wp,
    unsigned short* __restrict__ wqh, unsigned short* __restrict__ wql,
    unsigned short* __restrict__ wph, unsigned short* __restrict__ wpl) {
  int i = blockIdx.x * 256 + threadIdx.x;
  if (i < QKVC * DIM) {
    float v = wq[i];
    unsigned short h = f2bf(v);
    wqh[i] = h;
    wql[i] = f2bf(v - bf2f(h));
  }
  if (i < DIM * DIM) {
    float v = wp[i];
    unsigned short h = f2bf(v);
    wph[i] = h;
    wpl[i] = f2bf(v - bf2f(h));
  }
}

// ---------------- K1/K5: 1x1 conv MFMA GEMM, full-OC per 128-px block --------
// out[oc][p] = sum_ic w[oc][ic] x[ic][p].  grid (NPIX/128, nbz), block 256.
// Each wave: 32 px (2 B-frag groups) x all OC. W-loads pipeline in VGPRs
// (launch_bounds(256,1) lifts the 64-VGPR cap that serialized them at R7).
template<int OC, typename OutT>
__global__ __launch_bounds__(256, 1) void k_gemm1x1(
    const float* __restrict__ xin,
    const unsigned short* __restrict__ wh, const unsigned short* __restrict__ wl,
    OutT* __restrict__ out) {
  __shared__ __align__(16) unsigned short xhi[128 * 128];
  __shared__ __align__(16) unsigned short xlo[128 * 128];
  int t = threadIdx.x;
  int p0 = blockIdx.x * 128;
  const float* xb = xin + (size_t)blockIdx.y * DIM * NPIX + p0;

  if (t < 192) {
    int kg = t >> 4;    // 0..11 (8-k group)
    int f4c = t & 15;
    #pragma unroll
    for (int rep = 0; rep < 2; ++rep) {
      int f4 = f4c + rep * 16;  // float4 column 0..31
      float4 v[8];
      #pragma unroll
      for (int i = 0; i < 8; ++i)
        v[i] = *(const float4*)(xb + (size_t)(kg * 8 + i) * NPIX + f4 * 4);
      #pragma unroll
      for (int c = 0; c < 4; ++c) {
        int px = f4 * 4 + c;
        int u = kg ^ ((px & 7) ^ ((px >> 3) & 7));
        bf16x8 hv, lv;
        #pragma unroll
        for (int i = 0; i < 8; ++i) {
          float vv = ((const float*)&v[i])[c];
          unsigned short h = f2bf(vv);
          hv[i] = (short)h;
          lv[i] = (short)f2bf(vv - bf2f(h));
        }
        *(bf16x8*)&xhi[px * 128 + u * 8] = hv;
        *(bf16x8*)&xlo[px * 128 + u * 8] = lv;
      }
    }
  }
  __syncthreads();

  int lane = t & 63, wv = t >> 6;
  int r16 = lane & 15, kg8 = lane >> 4;

  // B fragments: 2 px-groups x 3 k-steps, hoisted
  bf16x8 bh[3][2], bl[3][2];
  #pragma unroll
  for (int nj = 0; nj < 2; ++nj) {
    int px = wv * 32 + nj * 16 + r16;
    int swz = (px & 7) ^ ((px >> 3) & 7);
    #pragma unroll
    for (int ks = 0; ks < 3; ++ks) {
      int u = (ks * 4 + kg8) ^ swz;
      bh[ks][nj] = *(const bf16x8*)&xhi[px * 128 + u * 8];
      bl[ks][nj] = *(const bf16x8*)&xlo[px * 128 + u * 8];
    }
  }

  f32x4 acc[OC / 16][2];
  #pragma unroll
  for (int mi = 0; mi < OC / 16; ++mi)
    #pragma unroll
    for (int nj = 0; nj < 2; ++nj) acc[mi][nj] = (f32x4){0.f, 0.f, 0.f, 0.f};

  #pragma unroll
  for (int mi = 0; mi < OC / 16; ++mi) {
    #pragma unroll
    for (int ks = 0; ks < 3; ++ks) {
      size_t woff = (size_t)(mi * 16 + r16) * DIM + ks * 32 + kg8 * 8;
      bf16x8 ah = *(const bf16x8*)(wh + woff);
      bf16x8 al = *(const bf16x8*)(wl + woff);
      #pragma unroll
      for (int nj = 0; nj < 2; ++nj) {
        acc[mi][nj] = __builtin_amdgcn_mfma_f32_16x16x32_bf16(ah, bh[ks][nj], acc[mi][nj], 0, 0, 0);
        acc[mi][nj] = __builtin_amdgcn_mfma_f32_16x16x32_bf16(ah, bl[ks][nj], acc[mi][nj], 0, 0, 0);
        acc[mi][nj] = __builtin_amdgcn_mfma_f32_16x16x32_bf16(al, bh[ks][nj], acc[mi][nj], 0, 0, 0);
      }
    }
  }

  OutT* op = out + (size_t)blockIdx.y * OC * NPIX + p0;
  #pragma unroll
  for (int mi = 0; mi < OC / 16; ++mi) {
    #pragma unroll
    for (int nj = 0; nj < 2; ++nj) {
      #pragma unroll
      for (int j = 0; j < 4; ++j) {
        int o = mi * 16 + kg8 * 4 + j;  // C/D: row=(lane>>4)*4+j, col=lane&15
        float v = acc[mi][nj][j];
        size_t idx = (size_t)o * NPIX + wv * 32 + nj * 16 + r16;
        if constexpr (sizeof(OutT) == 2) op[idx] = f2bf(v);
        else                             op[idx] = v;
      }
    }
  }
}

// ---------------- K2: depthwise 3x3 on bf16 input, split bf16 outputs --------
// grid (NPIX/1024, 288, nb), block 256. ch<192 -> qk planes; ch>=192 -> v planes
__global__ __launch_bounds__(256) void k_dw3x3_bf(
    const unsigned short* __restrict__ in, const float* __restrict__ w,
    unsigned short* __restrict__ qkout, unsigned short* __restrict__ vout) {
  int t = threadIdx.x;
  int p0 = (blockIdx.x * 256 + t) * 4;
  int ch = blockIdx.y;
  int b = blockIdx.z;
  const unsigned short* plane = in + ((size_t)b * QKVC + ch) * NPIX;
  int y = p0 >> 8, x0 = p0 & 255;
  const float* wc = w + ch * 9;
  float a0 = 0.f, a1 = 0.f, a2 = 0.f, a3 = 0.f;
  #pragma unroll
  for (int dy = -1; dy <= 1; ++dy) {
    int yy = y + dy;
    if (yy < 0 || yy >= HPIX) continue;
    const unsigned short* row = plane + (size_t)yy * WPIX + x0;
    ushort4 c4 = *(const ushort4*)row;
    float cx = bf2f(c4.x), cy = bf2f(c4.y), cz = bf2f(c4.z), cw = bf2f(c4.w);
    float l = (x0 > 0) ? bf2f(row[-1]) : 0.f;
    float r = (x0 < 252) ? bf2f(row[4]) : 0.f;
    float w0 = wc[(dy + 1) * 3], w1 = wc[(dy + 1) * 3 + 1], w2 = wc[(dy + 1) * 3 + 2];
    a0 = fmaf(w0, l,  fmaf(w1, cx, fmaf(w2, cy, a0)));
    a1 = fmaf(w0, cx, fmaf(w1, cy, fmaf(w2, cz, a1)));
    a2 = fmaf(w0, cy, fmaf(w1, cz, fmaf(w2, cw, a2)));
    a3 = fmaf(w0, cz, fmaf(w1, cw, fmaf(w2, r,  a3)));
  }
  ushort4 o = {f2bf(a0), f2bf(a1), f2bf(a2), f2bf(a3)};
  if (ch < 192) *(ushort4*)(qkout + ((size_t)b * 192 + ch) * NPIX + p0) = o;
  else          *(ushort4*)(vout + ((size_t)b * DIM + ch - 192) * NPIX + p0) = o;
}

// ---------------- K3a: MFMA partial grams + row norms, 1 wave/block ----------
// grid (96, 16, nb), block 64. Wave covers s in [cb*256, cb*256+256).
__global__ __launch_bounds__(64) void k_attn_part(
    const unsigned short* __restrict__ qkbuf, const float* __restrict__ mask,
    float* __restrict__ pbuf) {
  int g = blockIdx.x, cb = blockIdx.y, lb = blockIdx.z;
  int lane = threadIdx.x;
  int r16 = lane & 15, kg8 = lane >> 4;

  const unsigned short* qb = qkbuf + ((size_t)lb * 192 + g) * NPIX;
  const unsigned short* kb = qkbuf + ((size_t)lb * 192 + 96 + g) * NPIX;
  const float* mb = mask + ((size_t)lb * DIM + g) * NPIX;

  int rbase = ((r16 >> 2) << 6) * WPIX + ((r16 & 3) << 6);

  f32x4 aqk = {0.f, 0.f, 0.f, 0.f}, amm = {0.f, 0.f, 0.f, 0.f};
  float dq = 0.f, dk = 0.f;

  #pragma unroll
  for (int ks = 0; ks < 8; ++ks) {
    int s = cb * 256 + ks * 32 + kg8 * 8;
    int off = rbase + (s >> 6) * WPIX + (s & 63);
    bf16x8 qf = *(const bf16x8*)(qb + off);
    bf16x8 kf = *(const bf16x8*)(kb + off);
    float4 m0 = *(const float4*)(mb + off);
    float4 m1 = *(const float4*)(mb + off + 4);
    bf16x8 mf;
    mf[0] = (short)f2bf(m0.x); mf[1] = (short)f2bf(m0.y);
    mf[2] = (short)f2bf(m0.z); mf[3] = (short)f2bf(m0.w);
    mf[4] = (short)f2bf(m1.x); mf[5] = (short)f2bf(m1.y);
    mf[6] = (short)f2bf(m1.z); mf[7] = (short)f2bf(m1.w);
    aqk = __builtin_amdgcn_mfma_f32_16x16x32_bf16(qf, kf, aqk, 0, 0, 0);
    amm = __builtin_amdgcn_mfma_f32_16x16x32_bf16(mf, mf, amm, 0, 0, 0);
    #pragma unroll
    for (int i = 0; i < 8; ++i) {
      float qv = bf2f((unsigned short)qf[i]); dq = fmaf(qv, qv, dq);
      float kv = bf2f((unsigned short)kf[i]); dk = fmaf(kv, kv, dk);
    }
  }
  dq += __shfl_xor(dq, 16); dq += __shfl_xor(dq, 32);
  dk += __shfl_xor(dk, 16); dk += __shfl_xor(dk, 32);

  float* pb = pbuf + (((size_t)lb * DIM + g) * 16 + cb) * PSTRIDE;
  #pragma unroll
  for (int j = 0; j < 4; ++j) {
    int n = kg8 * 4 + j;
    pb[n * 16 + r16] = aqk[j];
    pb[256 + n * 16 + r16] = amm[j];
  }
  if (lane < 16) { pb[512 + r16] = dq; pb[528 + r16] = dk; }
}

// ---------------- K3b: reduce partials + softmax chain -> attn[16][16] -------
// grid (96, nb), block 256
__global__ __launch_bounds__(256) void k_attn_fin(
    const float* __restrict__ pbuf, const float* __restrict__ tx,
    const float* __restrict__ tm, float* __restrict__ attnbuf) {
  int g = blockIdx.x;
  int lb = blockIdx.y;
  int h = g / CPH;
  int t = threadIdx.x;
  int n = t >> 4, m = t & 15;

  const float* pb = pbuf + ((size_t)lb * DIM + g) * 16 * PSTRIDE;
  float gqk = 0.f, gmm = 0.f, dq = 0.f, dk = 0.f;
  #pragma unroll
  for (int c = 0; c < 16; ++c) {
    const float* p = pb + c * PSTRIDE;
    gqk += p[t];
    gmm += p[256 + t];
    dq  += p[512 + n];
    dk  += p[528 + m];
  }

  float qn = fmaxf(sqrtf(dq), EPSN);
  float km = fmaxf(sqrtf(dk), EPSN);

  float ax = gqk / (qn * km) * tx[h];
  float r0 = ax;
  #pragma unroll
  for (int off = 8; off; off >>= 1) r0 = fmaxf(r0, __shfl_xor(r0, off, 16));
  float e0 = expf(ax - r0), es0 = e0;
  #pragma unroll
  for (int off = 8; off; off >>= 1) es0 += __shfl_xor(es0, off, 16);
  float attx = e0 / es0;

  float am = gmm * tm[h];
  float s2 = am * am;
  #pragma unroll
  for (int off = 8; off; off >>= 1) s2 += __shfl_xor(s2, off, 16);
  am = am / fmaxf(sqrtf(s2), EPSN);
  float r1 = am;
  #pragma unroll
  for (int off = 8; off; off >>= 1) r1 = fmaxf(r1, __shfl_xor(r1, off, 16));
  float e1 = expf(am - r1), es1 = e1;
  #pragma unroll
  for (int off = 8; off; off >>= 1) es1 += __shfl_xor(es1, off, 16);
  float attm = e1 / es1;

  float aa = attx + attm;
  float r2 = aa;
  #pragma unroll
  for (int off = 8; off; off >>= 1) r2 = fmaxf(r2, __shfl_xor(r2, off, 16));
  float e2 = expf(aa - r2), es2 = e2;
  #pragma unroll
  for (int off = 8; off; off >>= 1) es2 += __shfl_xor(es2, off, 16);

  attnbuf[(((size_t)lb * DIM + g) << 8) + t] = e2 / es2;
}

// ---------------- K4: out_blk = attn @ v (bf16 v), written un-blockified -----
// grid (64 (hh), 96 (g), nb), block 256
__global__ __launch_bounds__(256) void k_pv(
    const unsigned short* __restrict__ vbuf, const float* __restrict__ attnbuf,
    float* __restrict__ tout) {
  int hh = blockIdx.x;
  int g = blockIdx.y;
  int lb = blockIdx.z;
  int t = threadIdx.x;
  int ww = t & 63, grp = t >> 6;

  __shared__ float vt[16][64];
  __shared__ float at[16][16];

  const unsigned short* vb = vbuf + ((size_t)lb * DIM + g) * NPIX;
  #pragma unroll
  for (int jj = 0; jj < 4; ++jj) {
    int mm = jj * 4 + grp;
    vt[mm][ww] = bf2f(vb[(size_t)(((mm >> 2) << 6) + hh) * WPIX + ((mm & 3) << 6) + ww]);
  }
  at[t >> 4][t & 15] = attnbuf[(((size_t)lb * DIM + g) << 8) + t];
  __syncthreads();

  float* ob = tout + ((size_t)lb * DIM + g) * NPIX;
  #pragma unroll
  for (int jj = 0; jj < 4; ++jj) {
    int nn = jj * 4 + grp;
    float acc = 0.f;
    #pragma unroll
    for (int mm = 0; mm < 16; ++mm)
      acc = fmaf(at[nn][mm], vt[mm][ww], acc);
    ob[(size_t)(((nn >> 2) << 6) + hh) * WPIX + ((nn & 3) << 6) + ww] = acc;
  }
}

extern "C" void kernel_launch(void* const* d_in, const int* in_sizes, int n_in,
                              void* d_out, int out_size, void* d_ws, size_t ws_size,
                              hipStream_t stream) {
  const float* x      = (const float*)d_in[0];
  const float* mask   = (const float*)d_in[1];
  const float* w_qkv  = (const float*)d_in[2];
  const float* w_dw   = (const float*)d_in[3];
  const float* w_proj = (const float*)d_in[4];
  const float* tx     = (const float*)d_in[5];
  const float* tm     = (const float*)d_in[6];
  float* out = (float*)d_out;

  const size_t wB     = (size_t)(2 * QKVC * DIM + 2 * DIM * DIM) * 2;  // 147456
  const size_t qkv1B  = (size_t)QKVC * NPIX * 2;   // 37.75 MB (>= tbuf 25.2 MB)
  const size_t qkB    = (size_t)192 * NPIX * 2;    // 25.2 MB
  const size_t vB     = (size_t)DIM * NPIX * 2;    // 12.6 MB
  const size_t atB    = (size_t)DIM * 256 * 4;
  const size_t pbB    = (size_t)DIM * 16 * PSTRIDE * 4;
  const size_t perB   = qkv1B + qkB + vB + atB + pbB;

  int nb = (ws_size >= wB + 4 * perB) ? 4 : 1;
  int npass = 4 / nb;

  char* base = (char*)d_ws;
  unsigned short* wqh = (unsigned short*)base;
  unsigned short* wql = wqh + QKVC * DIM;
  unsigned short* wph = wql + QKVC * DIM;
  unsigned short* wpl = wph + DIM * DIM;
  char* p = base + wB;
  unsigned short* qkv1bf = (unsigned short*)p;  p += (size_t)nb * qkv1B;
  float*          tbuf   = (float*)qkv1bf;      // alias: dead after dw
  unsigned short* qkbuf  = (unsigned short*)p;  p += (size_t)nb * qkB;
  unsigned short* vbuf   = (unsigned short*)p;  p += (size_t)nb * vB;
  float*          attn   = (float*)p;           p += (size_t)nb * atB;
  float*          pbuf   = (float*)p;

  dim3 blk(256);
  k_wprep<<<dim3((QKVC * DIM + 255) / 256), blk, 0, stream>>>(
      w_qkv, w_proj, wqh, wql, wph, wpl);

  for (int pass = 0; pass < npass; ++pass) {
    int b0 = pass * nb;
    k_gemm1x1<QKVC, unsigned short><<<dim3(NPIX / 128, nb), blk, 0, stream>>>(
        x + (size_t)b0 * DIM * NPIX, wqh, wql, qkv1bf);
    k_dw3x3_bf<<<dim3(NPIX / 1024, QKVC, nb), blk, 0, stream>>>(
        qkv1bf, w_dw, qkbuf, vbuf);
    k_attn_part<<<dim3(DIM, 16, nb), dim3(64), 0, stream>>>(
        qkbuf, mask + (size_t)b0 * DIM * NPIX, pbuf);
    k_attn_fin<<<dim3(DIM, nb), blk, 0, stream>>>(pbuf, tx, tm, attn);
    k_pv<<<dim3(64, DIM, nb), blk, 0, stream>>>(vbuf, attn, tbuf);
    k_gemm1x1<DIM, float><<<dim3(NPIX / 128, nb), blk, 0, stream>>>(
        tbuf, wph, wpl, out + (size_t)b0 * DIM * NPIX);
  }
}

// Round 9
// 250.448 us; speedup vs baseline: 2.5857x; 1.4380x over previous
//
#include <hip/hip_runtime.h>
#include <math.h>

#define HPIX 256
#define WPIX 256
#define NPIX (HPIX * WPIX)
#define DIM 96
#define QKVC 288
#define NHEAD 8
#define CPH 12
#define EPSN 1e-12f
#define PSTRIDE 544  // per (b,g,chunk) partial record: 256 gqk + 256 gmm + 16 dq + 16 dk

typedef __attribute__((ext_vector_type(8))) short bf16x8;
typedef __attribute__((ext_vector_type(4))) float f32x4;

__device__ __forceinline__ unsigned short f2bf(float f) {
  unsigned u = __float_as_uint(f);
  u += 0x7FFF + ((u >> 16) & 1);  // RNE
  return (unsigned short)(u >> 16);
}
__device__ __forceinline__ float bf2f(unsigned short h) {
  return __uint_as_float((unsigned)h << 16);
}

// ---------------- K0: weights -> plain bf16 (once per launch) ----------------
__global__ __launch_bounds__(256) void k_wprep(
    const float* __restrict__ wq, const float* __restrict__ wp,
    unsigned short* __restrict__ wqbf, unsigned short* __restrict__ wpbf) {
  int i = blockIdx.x * 256 + threadIdx.x;
  if (i < QKVC * DIM) wqbf[i] = f2bf(wq[i]);
  if (i < DIM * DIM)  wpbf[i] = f2bf(wp[i]);
}

// ---------------- K1/K5: 1x1 conv MFMA GEMM, W in LDS, X direct from global --
// out[oc][p] = sum_ic w[oc][ic] x[ic][p].  grid (NPIX/128, nb), block 256.
// Wave = 32 px (2 nj groups) x all OC. W staged once to LDS (stride 104 shorts
// -> conflict-free ds_read_b128); B-frags = 8 strided global loads each.
template<int OC, typename InT, typename OutT>
__global__ __launch_bounds__(256, 2) void k_gemm1x1(
    const InT* __restrict__ xin, const unsigned short* __restrict__ wbf,
    OutT* __restrict__ out) {
  __shared__ __align__(16) unsigned short wlds[OC * 104];
  int t = threadIdx.x;
  int p0 = blockIdx.x * 128;
  const InT* xb = xin + (size_t)blockIdx.y * DIM * NPIX;

  // stage W: OC x 96 shorts -> LDS rows padded to 104
  for (int i = t; i < OC * 12; i += 256) {
    int row = i / 12, seg = i % 12;
    bf16x8 w8 = *(const bf16x8*)(wbf + row * DIM + seg * 8);
    *(bf16x8*)&wlds[row * 104 + seg * 8] = w8;
  }
  __syncthreads();

  int lane = t & 63, wv = t >> 6;
  int r16 = lane & 15, kg8 = lane >> 4;

  // B fragments: 2 px-groups x 3 k-steps, from global (bf16-convert if fp32)
  bf16x8 bfr[3][2];
  #pragma unroll
  for (int nj = 0; nj < 2; ++nj) {
    int px = p0 + wv * 32 + nj * 16 + r16;
    #pragma unroll
    for (int ks = 0; ks < 3; ++ks) {
      int k0 = ks * 32 + kg8 * 8;
      bf16x8 b;
      #pragma unroll
      for (int i = 0; i < 8; ++i) {
        if constexpr (sizeof(InT) == 2) b[i] = (short)xb[(size_t)(k0 + i) * NPIX + px];
        else                            b[i] = (short)f2bf(xb[(size_t)(k0 + i) * NPIX + px]);
      }
      bfr[ks][nj] = b;
    }
  }

  f32x4 acc[OC / 16][2];
  #pragma unroll
  for (int mi = 0; mi < OC / 16; ++mi)
    #pragma unroll
    for (int nj = 0; nj < 2; ++nj) acc[mi][nj] = (f32x4){0.f, 0.f, 0.f, 0.f};

  #pragma unroll
  for (int mi = 0; mi < OC / 16; ++mi) {
    #pragma unroll
    for (int ks = 0; ks < 3; ++ks) {
      bf16x8 a = *(const bf16x8*)&wlds[(mi * 16 + r16) * 104 + ks * 32 + kg8 * 8];
      #pragma unroll
      for (int nj = 0; nj < 2; ++nj)
        acc[mi][nj] = __builtin_amdgcn_mfma_f32_16x16x32_bf16(a, bfr[ks][nj], acc[mi][nj], 0, 0, 0);
    }
  }

  OutT* op = out + (size_t)blockIdx.y * OC * NPIX + p0;
  #pragma unroll
  for (int mi = 0; mi < OC / 16; ++mi) {
    #pragma unroll
    for (int nj = 0; nj < 2; ++nj) {
      #pragma unroll
      for (int j = 0; j < 4; ++j) {
        int o = mi * 16 + kg8 * 4 + j;  // C/D: row=(lane>>4)*4+j, col=lane&15
        float v = acc[mi][nj][j];
        size_t idx = (size_t)o * NPIX + wv * 32 + nj * 16 + r16;
        if constexpr (sizeof(OutT) == 2) op[idx] = f2bf(v);
        else                             op[idx] = v;
      }
    }
  }
}

// ---------------- K2: depthwise 3x3 bf16, 8 px/thread, shfl x-halos ----------
// grid (NPIX/2048, 288, nb), block 256. ch<192 -> qk planes; ch>=192 -> v.
__global__ __launch_bounds__(256) void k_dw3x3_bf(
    const unsigned short* __restrict__ in, const float* __restrict__ w,
    unsigned short* __restrict__ qkout, unsigned short* __restrict__ vout) {
  int t = threadIdx.x;
  int p0 = (blockIdx.x * 256 + t) * 8;
  int ch = blockIdx.y, b = blockIdx.z;
  const unsigned short* plane = in + ((size_t)b * QKVC + ch) * NPIX;
  int y = p0 >> 8, x0 = p0 & 255;
  const float* wc = w + ch * 9;

  float acc[8];
  #pragma unroll
  for (int j = 0; j < 8; ++j) acc[j] = 0.f;

  #pragma unroll
  for (int dy = -1; dy <= 1; ++dy) {
    int yy = y + dy;
    float f[8];
    if (yy >= 0 && yy < HPIX) {
      bf16x8 v8 = *(const bf16x8*)(plane + (size_t)yy * WPIX + x0);
      #pragma unroll
      for (int j = 0; j < 8; ++j) f[j] = bf2f((unsigned short)v8[j]);
    } else {
      #pragma unroll
      for (int j = 0; j < 8; ++j) f[j] = 0.f;
    }
    float l = __shfl_up(f[7], 1);
    float r = __shfl_down(f[0], 1);
    if (x0 == 0) l = 0.f;
    if (x0 == 248) r = 0.f;
    float w0 = wc[(dy + 1) * 3], w1 = wc[(dy + 1) * 3 + 1], w2 = wc[(dy + 1) * 3 + 2];
    acc[0] = fmaf(w0, l, fmaf(w1, f[0], fmaf(w2, f[1], acc[0])));
    #pragma unroll
    for (int j = 1; j < 7; ++j)
      acc[j] = fmaf(w0, f[j - 1], fmaf(w1, f[j], fmaf(w2, f[j + 1], acc[j])));
    acc[7] = fmaf(w0, f[6], fmaf(w1, f[7], fmaf(w2, r, acc[7])));
  }

  bf16x8 o;
  #pragma unroll
  for (int j = 0; j < 8; ++j) o[j] = (short)f2bf(acc[j]);
  if (ch < 192) *(bf16x8*)(qkout + ((size_t)b * 192 + ch) * NPIX + p0) = o;
  else          *(bf16x8*)(vout + ((size_t)b * DIM + ch - 192) * NPIX + p0) = o;
}

// ---------------- K3a: MFMA partial grams + row norms, 1 wave/block ----------
// grid (96, 16, nb), block 64. Wave covers s in [cb*256, cb*256+256).
__global__ __launch_bounds__(64) void k_attn_part(
    const unsigned short* __restrict__ qkbuf, const float* __restrict__ mask,
    float* __restrict__ pbuf) {
  int g = blockIdx.x, cb = blockIdx.y, lb = blockIdx.z;
  int lane = threadIdx.x;
  int r16 = lane & 15, kg8 = lane >> 4;

  const unsigned short* qb = qkbuf + ((size_t)lb * 192 + g) * NPIX;
  const unsigned short* kb = qkbuf + ((size_t)lb * 192 + 96 + g) * NPIX;
  const float* mb = mask + ((size_t)lb * DIM + g) * NPIX;

  int rbase = ((r16 >> 2) << 6) * WPIX + ((r16 & 3) << 6);

  f32x4 aqk = {0.f, 0.f, 0.f, 0.f}, amm = {0.f, 0.f, 0.f, 0.f};
  float dq = 0.f, dk = 0.f;

  #pragma unroll
  for (int ks = 0; ks < 8; ++ks) {
    int s = cb * 256 + ks * 32 + kg8 * 8;
    int off = rbase + (s >> 6) * WPIX + (s & 63);
    bf16x8 qf = *(const bf16x8*)(qb + off);
    bf16x8 kf = *(const bf16x8*)(kb + off);
    float4 m0 = *(const float4*)(mb + off);
    float4 m1 = *(const float4*)(mb + off + 4);
    bf16x8 mf;
    mf[0] = (short)f2bf(m0.x); mf[1] = (short)f2bf(m0.y);
    mf[2] = (short)f2bf(m0.z); mf[3] = (short)f2bf(m0.w);
    mf[4] = (short)f2bf(m1.x); mf[5] = (short)f2bf(m1.y);
    mf[6] = (short)f2bf(m1.z); mf[7] = (short)f2bf(m1.w);
    aqk = __builtin_amdgcn_mfma_f32_16x16x32_bf16(qf, kf, aqk, 0, 0, 0);
    amm = __builtin_amdgcn_mfma_f32_16x16x32_bf16(mf, mf, amm, 0, 0, 0);
    #pragma unroll
    for (int i = 0; i < 8; ++i) {
      float qv = bf2f((unsigned short)qf[i]); dq = fmaf(qv, qv, dq);
      float kv = bf2f((unsigned short)kf[i]); dk = fmaf(kv, kv, dk);
    }
  }
  dq += __shfl_xor(dq, 16); dq += __shfl_xor(dq, 32);
  dk += __shfl_xor(dk, 16); dk += __shfl_xor(dk, 32);

  float* pb = pbuf + (((size_t)lb * DIM + g) * 16 + cb) * PSTRIDE;
  #pragma unroll
  for (int j = 0; j < 4; ++j) {
    int n = kg8 * 4 + j;
    pb[n * 16 + r16] = aqk[j];
    pb[256 + n * 16 + r16] = amm[j];
  }
  if (lane < 16) { pb[512 + r16] = dq; pb[528 + r16] = dk; }
}

// ---------------- K3b: reduce partials + softmax chain -> attn[16][16] -------
// grid (96, nb), block 256
__global__ __launch_bounds__(256) void k_attn_fin(
    const float* __restrict__ pbuf, const float* __restrict__ tx,
    const float* __restrict__ tm, float* __restrict__ attnbuf) {
  int g = blockIdx.x;
  int lb = blockIdx.y;
  int h = g / CPH;
  int t = threadIdx.x;
  int n = t >> 4, m = t & 15;

  const float* pb = pbuf + ((size_t)lb * DIM + g) * 16 * PSTRIDE;
  float gqk = 0.f, gmm = 0.f, dq = 0.f, dk = 0.f;
  #pragma unroll
  for (int c = 0; c < 16; ++c) {
    const float* p = pb + c * PSTRIDE;
    gqk += p[t];
    gmm += p[256 + t];
    dq  += p[512 + n];
    dk  += p[528 + m];
  }

  float qn = fmaxf(sqrtf(dq), EPSN);
  float km = fmaxf(sqrtf(dk), EPSN);

  float ax = gqk / (qn * km) * tx[h];
  float r0 = ax;
  #pragma unroll
  for (int off = 8; off; off >>= 1) r0 = fmaxf(r0, __shfl_xor(r0, off, 16));
  float e0 = expf(ax - r0), es0 = e0;
  #pragma unroll
  for (int off = 8; off; off >>= 1) es0 += __shfl_xor(es0, off, 16);
  float attx = e0 / es0;

  float am = gmm * tm[h];
  float s2 = am * am;
  #pragma unroll
  for (int off = 8; off; off >>= 1) s2 += __shfl_xor(s2, off, 16);
  am = am / fmaxf(sqrtf(s2), EPSN);
  float r1 = am;
  #pragma unroll
  for (int off = 8; off; off >>= 1) r1 = fmaxf(r1, __shfl_xor(r1, off, 16));
  float e1 = expf(am - r1), es1 = e1;
  #pragma unroll
  for (int off = 8; off; off >>= 1) es1 += __shfl_xor(es1, off, 16);
  float attm = e1 / es1;

  float aa = attx + attm;
  float r2 = aa;
  #pragma unroll
  for (int off = 8; off; off >>= 1) r2 = fmaxf(r2, __shfl_xor(r2, off, 16));
  float e2 = expf(aa - r2), es2 = e2;
  #pragma unroll
  for (int off = 8; off; off >>= 1) es2 += __shfl_xor(es2, off, 16);

  attnbuf[(((size_t)lb * DIM + g) << 8) + t] = e2 / es2;
}

// ---------------- K4: out_blk = attn @ v (bf16), t written bf16 --------------
// grid (64 (hh), 96 (g), nb), block 256
__global__ __launch_bounds__(256) void k_pv(
    const unsigned short* __restrict__ vbuf, const float* __restrict__ attnbuf,
    unsigned short* __restrict__ tout) {
  int hh = blockIdx.x;
  int g = blockIdx.y;
  int lb = blockIdx.z;
  int t = threadIdx.x;
  int ww = t & 63, grp = t >> 6;

  __shared__ float vt[16][64];
  __shared__ float at[16][16];

  const unsigned short* vb = vbuf + ((size_t)lb * DIM + g) * NPIX;
  #pragma unroll
  for (int jj = 0; jj < 4; ++jj) {
    int mm = jj * 4 + grp;
    vt[mm][ww] = bf2f(vb[(size_t)(((mm >> 2) << 6) + hh) * WPIX + ((mm & 3) << 6) + ww]);
  }
  at[t >> 4][t & 15] = attnbuf[(((size_t)lb * DIM + g) << 8) + t];
  __syncthreads();

  unsigned short* ob = tout + ((size_t)lb * DIM + g) * NPIX;
  #pragma unroll
  for (int jj = 0; jj < 4; ++jj) {
    int nn = jj * 4 + grp;
    float acc = 0.f;
    #pragma unroll
    for (int mm = 0; mm < 16; ++mm)
      acc = fmaf(at[nn][mm], vt[mm][ww], acc);
    ob[(size_t)(((nn >> 2) << 6) + hh) * WPIX + ((nn & 3) << 6) + ww] = f2bf(acc);
  }
}

extern "C" void kernel_launch(void* const* d_in, const int* in_sizes, int n_in,
                              void* d_out, int out_size, void* d_ws, size_t ws_size,
                              hipStream_t stream) {
  const float* x      = (const float*)d_in[0];
  const float* mask   = (const float*)d_in[1];
  const float* w_qkv  = (const float*)d_in[2];
  const float* w_dw   = (const float*)d_in[3];
  const float* w_proj = (const float*)d_in[4];
  const float* tx     = (const float*)d_in[5];
  const float* tm     = (const float*)d_in[6];
  float* out = (float*)d_out;

  const size_t wB     = (size_t)(QKVC * DIM + DIM * DIM) * 2;  // 73728
  const size_t qkv1B  = (size_t)QKVC * NPIX * 2;   // 37.75 MB (>= tbuf 12.6 MB bf16)
  const size_t qkB    = (size_t)192 * NPIX * 2;    // 25.2 MB
  const size_t vB     = (size_t)DIM * NPIX * 2;    // 12.6 MB
  const size_t atB    = (size_t)DIM * 256 * 4;
  const size_t pbB    = (size_t)DIM * 16 * PSTRIDE * 4;
  const size_t perB   = qkv1B + qkB + vB + atB + pbB;

  int nb = (ws_size >= wB + 4 * perB) ? 4 : 1;
  int npass = 4 / nb;

  char* base = (char*)d_ws;
  unsigned short* wqbf = (unsigned short*)base;
  unsigned short* wpbf = wqbf + QKVC * DIM;
  char* p = base + wB;
  unsigned short* qkv1bf = (unsigned short*)p;  p += (size_t)nb * qkv1B;
  unsigned short* tbuf   = qkv1bf;              // alias: dead after dw
  unsigned short* qkbuf  = (unsigned short*)p;  p += (size_t)nb * qkB;
  unsigned short* vbuf   = (unsigned short*)p;  p += (size_t)nb * vB;
  float*          attn   = (float*)p;           p += (size_t)nb * atB;
  float*          pbuf   = (float*)p;

  dim3 blk(256);
  k_wprep<<<dim3((QKVC * DIM + 255) / 256), blk, 0, stream>>>(
      w_qkv, w_proj, wqbf, wpbf);

  for (int pass = 0; pass < npass; ++pass) {
    int b0 = pass * nb;
    k_gemm1x1<QKVC, float, unsigned short><<<dim3(NPIX / 128, nb), blk, 0, stream>>>(
        x + (size_t)b0 * DIM * NPIX, wqbf, qkv1bf);
    k_dw3x3_bf<<<dim3(NPIX / 2048, QKVC, nb), blk, 0, stream>>>(
        qkv1bf, w_dw, qkbuf, vbuf);
    k_attn_part<<<dim3(DIM, 16, nb), dim3(64), 0, stream>>>(
        qkbuf, mask + (size_t)b0 * DIM * NPIX, pbuf);
    k_attn_fin<<<dim3(DIM, nb), blk, 0, stream>>>(pbuf, tx, tm, attn);
    k_pv<<<dim3(64, DIM, nb), blk, 0, stream>>>(vbuf, attn, tbuf);
    k_gemm1x1<DIM, unsigned short, float><<<dim3(NPIX / 128, nb), blk, 0, stream>>>(
        tbuf, wpbf, out + (size_t)b0 * DIM * NPIX);
  }
}